// Round 13
// baseline (408.398 us; speedup 1.0000x reference)
//
#include <hip/hip_runtime.h>
#include <hip/hip_bf16.h>
#include <stdint.h>

#define B_ 4
#define S_ 2048
#define E_ 2048
#define H_ 16
#define D_ 128
#define M_ (B_ * S_)  // 8192 rows

typedef unsigned short ushort_t;
typedef unsigned int uint_t;
typedef __attribute__((ext_vector_type(4))) float f32x4;
typedef __attribute__((ext_vector_type(2))) uint_t u32x2;
typedef __attribute__((ext_vector_type(8))) short bf16x8;

__device__ __forceinline__ ushort_t f2bf(float f) {
  uint_t u = __float_as_uint(f);
  u += 0x7FFFu + ((u >> 16) & 1u);  // RNE
  return (ushort_t)(u >> 16);
}
__device__ __forceinline__ float bf2f(ushort_t h) {
  return __uint_as_float(((uint_t)h) << 16);
}
__device__ __forceinline__ uint_t cvt_pk_bf16(float lo, float hi) {
  uint_t r;
  asm("v_cvt_pk_bf16_f32 %0, %1, %2" : "=v"(r) : "v"(lo), "v"(hi));
  return r;
}
__device__ __forceinline__ float fexp2(float x) {  // bare v_exp_f32 (2^x)
  float r;
  asm("v_exp_f32 %0, %1" : "=v"(r) : "v"(x));
  return r;
}

#define GLOAD_LDS16(gp, lp)                                   \
  __builtin_amdgcn_global_load_lds(                           \
      (__attribute__((address_space(1))) void*)(gp),          \
      (__attribute__((address_space(3))) void*)(lp), 16, 0, 0)

// ---------------------------------------------------------------- converts
__global__ void f32_to_bf16(const float* __restrict__ in, ushort_t* __restrict__ out,
                            size_t n4) {
  const size_t stride = (size_t)gridDim.x * blockDim.x;
  for (size_t i = (size_t)blockIdx.x * blockDim.x + threadIdx.x; i < n4; i += stride) {
    const f32x4 f = __builtin_nontemporal_load((const f32x4*)in + i);
    u32x2 o;
    o[0] = (uint_t)f2bf(f[0]) | ((uint_t)f2bf(f[1]) << 16);
    o[1] = (uint_t)f2bf(f[2]) | ((uint_t)f2bf(f[3]) << 16);
    __builtin_nontemporal_store(o, (u32x2*)out + i);
  }
}

// fused 4-weight convert: dst = 4 contiguous [E][E] bf16 regions
__global__ void w4_to_bf16(const float* __restrict__ w0, const float* __restrict__ w1,
                           const float* __restrict__ w2, const float* __restrict__ w3,
                           ushort_t* __restrict__ out) {
  const size_t n4 = (size_t)E_ * E_;  // total float4 chunks over all 4 weights
  const size_t per = n4 >> 2;         // 2^20 chunks per weight
  const size_t stride = (size_t)gridDim.x * blockDim.x;
  for (size_t c = (size_t)blockIdx.x * blockDim.x + threadIdx.x; c < n4; c += stride) {
    const int wsel = (int)(c / per);
    const size_t off = c - (size_t)wsel * per;
    const float* src = wsel == 0 ? w0 : (wsel == 1 ? w1 : (wsel == 2 ? w2 : w3));
    const f32x4 f = __builtin_nontemporal_load((const f32x4*)src + off);
    u32x2 o;
    o[0] = (uint_t)f2bf(f[0]) | ((uint_t)f2bf(f[1]) << 16);
    o[1] = (uint_t)f2bf(f[2]) | ((uint_t)f2bf(f[3]) << 16);
    __builtin_nontemporal_store(o, (u32x2*)out + c);
  }
}

// ---------------------------------------------------------------- RoPE cos/sin table
__global__ void rope_table(float2* __restrict__ tab) {
  const int i = blockIdx.x * 256 + threadIdx.x;  // grid 512 -> 131072
  const int s = i >> 6, p = i & 63;
  const float inv = exp2f(-0.20762050593046f * (float)p);  // 10000^(-2p/128)
  float sn, cs;
  sincosf((float)s * inv, &sn, &cs);
  tab[i] = make_float2(cs, sn);
}

// ================================================================ 8-phase GEMM (round-8 proven)
#define G8_BARR asm volatile("s_barrier" ::: "memory")
#define G8_VM6 asm volatile("s_waitcnt vmcnt(6)" ::: "memory")
#define G8_VM0 asm volatile("s_waitcnt vmcnt(0)" ::: "memory")
#define G8_LGKM0                                         \
  do {                                                   \
    asm volatile("s_waitcnt lgkmcnt(0)" ::: "memory");   \
    __builtin_amdgcn_sched_barrier(0);                   \
  } while (0)
#define G8_RDB(bp, kk)                                                         \
  _Pragma("unroll") for (int ni = 0; ni < 4; ni++) bfr[ni] =                   \
      *(const bf16x8*)((bp) + bBase + (kk)*16384 + ni * 1024);
#define G8_RDA(bp, kk, mh)                                                     \
  _Pragma("unroll") for (int ai = 0; ai < 4; ai++) af[ai] =                    \
      *(const bf16x8*)((bp) + aBase + (kk)*16384 + (mh)*4096 + ai * 1024);
#define G8_MM(mh)                                                              \
  __builtin_amdgcn_s_setprio(1);                                               \
  _Pragma("unroll") for (int ai = 0; ai < 4; ai++)                             \
      _Pragma("unroll") for (int ni = 0; ni < 4; ni++) acc[(mh)*4 + ai][ni] =  \
          __builtin_amdgcn_mfma_f32_16x16x32_bf16(af[ai], bfr[ni],             \
                                                  acc[(mh)*4 + ai][ni], 0, 0, 0); \
  __builtin_amdgcn_s_setprio(0);

// MODE 0: bf16. MODE 1: f32. MODE 2: bf16 + RoPE(table)*sc.
// MODE 3: bf16 TRANSPOSED V-output (fused transpose_v).
template <int MODE>
__global__ __launch_bounds__(512, 2) void gemm8p(const ushort_t* __restrict__ A,
                                                 const ushort_t* __restrict__ Bw,
                                                 const float* __restrict__ bias,
                                                 const float2* __restrict__ tab,
                                                 const float sc,
                                                 void* __restrict__ Cv) {
  __shared__ __align__(16) char lds[131072];
  const int tid = threadIdx.x;
  const int w = tid >> 6, l = tid & 63, g = l >> 4, ln = l & 15;
  const int wm = w >> 2, wn = w & 3;

  const int flat = blockIdx.x;  // 256 blocks; XCD-chunked bijective swizzle
  const int swz = (flat & 7) * 32 + (flat >> 3);
  const int m0 = (swz >> 3) * 256, n0 = (swz & 7) * 256;

  const ushort_t* Ab = A + (size_t)m0 * E_;
  const ushort_t* Bb = Bw + (size_t)n0 * E_;

  int srcRow[2], srcCc[2];
#pragma unroll
  for (int i = 0; i < 2; i++) {
    const int c = i * 512 + tid;       // chunk 0..1023 of one 16KB slab
    const int r2 = c >> 3;             // row-pair 0..127
    const int j = (c & 7) ^ (r2 & 7);  // inverse chunk-XOR swizzle
    srcRow[i] = 2 * r2 + (j >> 2);
    srcCc[i] = (j & 3) * 8;
  }

  auto STAGE = [&](int t_, int mat, int kk) {
    char* dst = lds + (t_ & 1) * 65536 + mat * 32768 + kk * 16384;
    const ushort_t* src = mat ? Bb : Ab;
#pragma unroll
    for (int i = 0; i < 2; i++)
      GLOAD_LDS16(src + (size_t)srcRow[i] * E_ + t_ * 64 + kk * 32 + srcCc[i],
                  dst + (i * 512 + w * 64) * 16);
  };

  const int rp = ln >> 1;
  const int chunkl = ((((ln & 1) << 2) | g) ^ rp);
  const int aBase = wm * 8192 + rp * 128 + chunkl * 16;
  const int bBase = 32768 + wn * 4096 + rp * 128 + chunkl * 16;

  f32x4 acc[8][4];
#pragma unroll
  for (int mi = 0; mi < 8; mi++)
#pragma unroll
    for (int ni = 0; ni < 4; ni++)
#pragma unroll
      for (int r = 0; r < 4; r++) acc[mi][ni][r] = 0.f;

  // prologue: T0 all 4 slabs, T1 {Bk0, Ak0, Bk1}
  STAGE(0, 1, 0); STAGE(0, 0, 0); STAGE(0, 1, 1); STAGE(0, 0, 1);
  STAGE(1, 1, 0); STAGE(1, 0, 0); STAGE(1, 1, 1);
  G8_VM6; G8_BARR;

  const char* b0 = lds;
  const char* b1 = lds + 65536;
  bf16x8 af[4], bfr[4];

  for (int it = 0; it < 15; ++it) {  // 2 K-tiles per iteration
    const int t2 = 2 * it;
    G8_RDB(b0, 0); G8_RDA(b0, 0, 0); STAGE(t2 + 1, 0, 1); G8_BARR; G8_LGKM0; G8_MM(0); G8_BARR;
    G8_RDA(b0, 0, 1);                STAGE(t2 + 2, 1, 0); G8_BARR; G8_LGKM0; G8_MM(1); G8_BARR;
    G8_RDB(b0, 1); G8_RDA(b0, 1, 0); STAGE(t2 + 2, 0, 0); G8_BARR; G8_LGKM0; G8_MM(0); G8_BARR;
    G8_RDA(b0, 1, 1);                STAGE(t2 + 2, 1, 1); G8_BARR; G8_LGKM0; G8_MM(1); G8_VM6; G8_BARR;
    G8_RDB(b1, 0); G8_RDA(b1, 0, 0); STAGE(t2 + 2, 0, 1); G8_BARR; G8_LGKM0; G8_MM(0); G8_BARR;
    G8_RDA(b1, 0, 1);                STAGE(t2 + 3, 1, 0); G8_BARR; G8_LGKM0; G8_MM(1); G8_BARR;
    G8_RDB(b1, 1); G8_RDA(b1, 1, 0); STAGE(t2 + 3, 0, 0); G8_BARR; G8_LGKM0; G8_MM(0); G8_BARR;
    G8_RDA(b1, 1, 1);                STAGE(t2 + 3, 1, 1); G8_BARR; G8_LGKM0; G8_MM(1); G8_VM6; G8_BARR;
  }
  // tail: T30 (b0), T31 (b1)
  G8_RDB(b0, 0); G8_RDA(b0, 0, 0); STAGE(31, 0, 1); G8_BARR; G8_LGKM0; G8_MM(0); G8_BARR;
  G8_RDA(b0, 0, 1);                                 G8_BARR; G8_LGKM0; G8_MM(1); G8_BARR;
  G8_RDB(b0, 1); G8_RDA(b0, 1, 0);                  G8_BARR; G8_LGKM0; G8_MM(0); G8_BARR;
  G8_RDA(b0, 1, 1);                                 G8_BARR; G8_LGKM0; G8_MM(1); G8_VM0; G8_BARR;
  G8_RDB(b1, 0); G8_RDA(b1, 0, 0);                  G8_BARR; G8_LGKM0; G8_MM(0); G8_BARR;
  G8_RDA(b1, 0, 1);                                 G8_BARR; G8_LGKM0; G8_MM(1); G8_BARR;
  G8_RDB(b1, 1); G8_RDA(b1, 1, 0);                  G8_BARR; G8_LGKM0; G8_MM(0); G8_BARR;
  G8_RDA(b1, 1, 1);                                 G8_BARR; G8_LGKM0; G8_MM(1);

  // ---------------- epilogue
  float bv[4];
#pragma unroll
  for (int ni = 0; ni < 4; ni++) bv[ni] = bias[n0 + wn * 64 + ni * 16 + ln];

  if (MODE == 3) {
    // fused V-transpose: acc -> Ct[col][row] bf16 in LDS (XOR swizzle), then
    // fully-coalesced b128 stores along s.
    G8_BARR;  // all waves past their last LDS read of the main loop
#pragma unroll
    for (int mi = 0; mi < 8; mi++)
#pragma unroll
      for (int ni = 0; ni < 4; ni++) {
        const int col = wn * 64 + ni * 16 + ln;       // local col (d-dim) 0..255
        const int row0 = wm * 128 + mi * 16 + g * 4;  // local row (s-dim) 0..252
        const uint_t lo = cvt_pk_bf16(acc[mi][ni][0] + bv[ni], acc[mi][ni][1] + bv[ni]);
        const uint_t hi = cvt_pk_bf16(acc[mi][ni][2] + bv[ni], acc[mi][ni][3] + bv[ni]);
        const int byte = (col * 512 + row0 * 2) ^ ((col & 7) << 4);
        *(uint2*)(lds + byte) = make_uint2(lo, hi);
      }
    G8_BARR;
    const int bb = m0 >> 11, s0b = m0 & (S_ - 1);
#pragma unroll
    for (int i = 0; i < 16; i++) {
      const int c = i * 512 + tid;
      const int colL = c >> 5, q = c & 31;  // col 0..255, 16B chunk 0..31
      const int byte = (colL * 512 + q * 16) ^ ((colL & 7) << 4);
      const bf16x8 vv = *(const bf16x8*)(lds + byte);
      const int gcol = n0 + colL;
      const int hh = gcol >> 7, d = gcol & 127;
      *(bf16x8*)((ushort_t*)Cv + (((size_t)(bb * H_ + hh) * D_ + d) * S_ + s0b + q * 8)) = vv;
    }
    return;
  }

#pragma unroll
  for (int mi = 0; mi < 8; mi++)
#pragma unroll
    for (int ni = 0; ni < 4; ni++) {
      const int col = n0 + wn * 64 + ni * 16 + ln;
      const int p = (col & 127) >> 1;
      const float sgn = (col & 1) ? 1.f : -1.f;
      const int row0 = m0 + wm * 128 + mi * 16 + g * 4;
#pragma unroll
      for (int r = 0; r < 4; r++) {
        const float v = acc[mi][ni][r] + bv[ni];
        if (MODE == 1) {
          ((float*)Cv)[(size_t)(row0 + r) * E_ + col] = v;
        } else if (MODE == 2) {
          const float partner = __shfl_xor(v, 1);
          const float2 t = tab[((row0 + r) & (S_ - 1)) * 64 + p];
          ((ushort_t*)Cv)[(size_t)(row0 + r) * E_ + col] =
              f2bf((v * t.x + sgn * partner * t.y) * sc);
        } else {
          ((ushort_t*)Cv)[(size_t)(row0 + r) * E_ + col] = f2bf(v);
        }
      }
    }
}

// ---------------------------------------------------------------- flash attention (causal)
// QBLK=256 / 8 waves / 512 thr / 1 block/CU (LDS 96 KB). K/V staged ONCE per 256
// q-rows (halves staging + FETCH vs QBLK=128 x 2 blocks). Balanced pairs (u,7-u)
// -> uniform 36 tiles/block; grid 256, XCD = bh%8. Math identical to round-10
// (exp2-domain softmax, defer-max 11.5, counted vmcnt, swapped QK^T).
__global__ __launch_bounds__(512, 1) void attn_fwd(const ushort_t* __restrict__ Q,
                                                   const ushort_t* __restrict__ K,
                                                   const ushort_t* __restrict__ Vt,
                                                   ushort_t* __restrict__ O) {
  const int flat = blockIdx.x;  // 256 blocks
  const int pair = flat >> 6;   // 0..3
  const int bh = flat & 63;     // XCD = bh%8 for all 4 pair-blocks of this bh
  const int b = bh >> 4, h = bh & 15;
  const int tid = threadIdx.x;
  const int w = tid >> 6, l = tid & 63, g = l >> 4, ln = l & 15;

  __shared__ ushort_t Ks[2][64 * 128];  // 32 KB
  __shared__ ushort_t Vs[2][128 * 64];  // 32 KB
  __shared__ ushort_t Ps[8][32 * 64];   // 32 KB, XOR-swizzled rows

  const ushort_t* Kb = K + (size_t)(b * S_) * E_ + h * D_;
  const ushort_t* Vb = Vt + (size_t)(b * H_ + h) * D_ * S_;
  const float scale2 = 0.12751744528276693f;  // D^-0.5 * log2(e)

  // 512 threads: 2 K-chunks + 2 V-chunks per thread per tile (4 loads/wave-lane)
#define STAGE_KV(buf, kv0_)                                                      \
  do {                                                                           \
    _Pragma("unroll") for (int i = 0; i < 2; i++) {                              \
      const int c = i * 512 + tid;                                               \
      const int row = c >> 4, sl = c & 15;                                       \
      const int gs = sl ^ (row & 7);                                             \
      GLOAD_LDS16(Kb + (size_t)((kv0_) + row) * E_ + gs * 8,                     \
                  (char*)(&Ks[buf][0]) + (i * 512 + w * 64) * 16);               \
    }                                                                            \
    _Pragma("unroll") for (int i = 0; i < 2; i++) {                              \
      const int c = i * 512 + tid;                                               \
      const int row = c >> 3, sl = c & 7;                                        \
      const int gs = sl ^ (row & 7);                                             \
      GLOAD_LDS16(Vb + (size_t)row * S_ + (kv0_) + gs * 8,                       \
                  (char*)(&Vs[buf][0]) + (i * 512 + w * 64) * 16);               \
    }                                                                            \
  } while (0)

  for (int pass = 0; pass < 2; pass++) {
    const int u = (pass == 0) ? pair : (7 - pair);
    const int q0 = u * 256;
    const int wrow0 = q0 + w * 32;

    bf16x8 qf[2][4];
    {
      const ushort_t* qb = Q + (size_t)(b * S_ + wrow0) * E_ + h * D_;
#pragma unroll
      for (int mi = 0; mi < 2; mi++)
#pragma unroll
        for (int kk = 0; kk < 4; kk++) {
          bf16x8 v = *(const bf16x8*)(qb + (size_t)(mi * 16 + ln) * E_ + kk * 32 + g * 8);
#pragma unroll
          for (int j = 0; j < 8; j++) v[j] = (short)f2bf(bf2f((ushort_t)v[j]) * scale2);
          qf[mi][kk] = v;
        }
    }

    f32x4 oacc[2][8];
#pragma unroll
    for (int mi = 0; mi < 2; mi++)
#pragma unroll
      for (int nd = 0; nd < 8; nd++)
#pragma unroll
        for (int r = 0; r < 4; r++) oacc[mi][nd][r] = 0.f;
    float mrun[2], srun[2];
#pragma unroll
    for (int mi = 0; mi < 2; mi++) {
      mrun[mi] = -__builtin_inff();
      srun[mi] = 0.f;
    }

    const int ntu = 4 * u + 4;
    STAGE_KV(0, 0);

    for (int t = 0; t < ntu; t++) {
      const int kv0 = t * 64;
      const int cur = t & 1;
      if (t + 1 < ntu) {
        STAGE_KV(cur ^ 1, kv0 + 64);
        asm volatile("s_waitcnt vmcnt(4)" ::: "memory");  // tile t landed; t+1 in flight
      } else {
        asm volatile("s_waitcnt vmcnt(0)" ::: "memory");
      }
      __builtin_amdgcn_s_barrier();
      __builtin_amdgcn_sched_barrier(0);

      if (kv0 <= wrow0 + 31) {
        const ushort_t* Kst = &Ks[cur][0];
        const ushort_t* Vst = &Vs[cur][0];
        f32x4 sa[2][4];
#pragma unroll
        for (int mi = 0; mi < 2; mi++)
#pragma unroll
          for (int ni = 0; ni < 4; ni++)
#pragma unroll
            for (int r = 0; r < 4; r++) sa[mi][ni][r] = 0.f;
        __builtin_amdgcn_s_setprio(1);
#pragma unroll
        for (int kk = 0; kk < 4; kk++) {
          bf16x8 kf[4];
#pragma unroll
          for (int ni = 0; ni < 4; ni++) {
            const int row = ni * 16 + ln;
            const int sl = (kk * 4 + g) ^ (row & 7);
            kf[ni] = *(const bf16x8*)(Kst + row * 128 + sl * 8);
          }
#pragma unroll
          for (int mi = 0; mi < 2; mi++)
#pragma unroll
            for (int ni = 0; ni < 4; ni++)
              sa[mi][ni] =
                  __builtin_amdgcn_mfma_f32_16x16x32_bf16(kf[ni], qf[mi][kk], sa[mi][ni], 0, 0, 0);
        }
        __builtin_amdgcn_s_setprio(0);
        if (kv0 + 63 > wrow0) {
#pragma unroll
          for (int mi = 0; mi < 2; mi++) {
            const int lim = wrow0 + mi * 16 + ln - kv0;
#pragma unroll
            for (int ni = 0; ni < 4; ni++)
#pragma unroll
              for (int r = 0; r < 4; r++)
                if (ni * 16 + g * 4 + r > lim) sa[mi][ni][r] = -__builtin_inff();
          }
        }
#pragma unroll
        for (int mi = 0; mi < 2; mi++) {
          float vmax = -__builtin_inff();
#pragma unroll
          for (int ni = 0; ni < 4; ni++)
#pragma unroll
            for (int r = 0; r < 4; r++) vmax = fmaxf(vmax, sa[mi][ni][r]);
          vmax = fmaxf(vmax, __shfl_xor(vmax, 16));
          vmax = fmaxf(vmax, __shfl_xor(vmax, 32));
          if (!__all(vmax - mrun[mi] <= 11.5f)) {  // defer-max (exp2 domain)
            const float mnew = fmaxf(mrun[mi], vmax);
            const float fs = fexp2(mrun[mi] - mnew);
            mrun[mi] = mnew;
            srun[mi] *= fs;
#pragma unroll
            for (int nd = 0; nd < 8; nd++)
#pragma unroll
              for (int r = 0; r < 4; r++) oacc[mi][nd][r] *= fs;
          }
          const float m = mrun[mi];
          float psum = 0.f;
#pragma unroll
          for (int ni = 0; ni < 4; ni++) {
            float p0 = fexp2(sa[mi][ni][0] - m);
            float p1 = fexp2(sa[mi][ni][1] - m);
            float p2 = fexp2(sa[mi][ni][2] - m);
            float p3 = fexp2(sa[mi][ni][3] - m);
            psum += (p0 + p1) + (p2 + p3);
            const int byteW =
                (((mi * 16 + ln) * 64 + ni * 16 + g * 4) * 2) ^ ((ln & 7) << 4);
            *(uint2*)((char*)(&Ps[w][0]) + byteW) =
                make_uint2(cvt_pk_bf16(p0, p1), cvt_pk_bf16(p2, p3));
          }
          psum += __shfl_xor(psum, 16);
          psum += __shfl_xor(psum, 32);
          srun[mi] += psum;
        }
        asm volatile("s_waitcnt lgkmcnt(0)" ::: "memory");  // per-wave P write->read
        __builtin_amdgcn_sched_barrier(0);
        __builtin_amdgcn_s_setprio(1);
#pragma unroll
        for (int ks = 0; ks < 2; ks++) {
          bf16x8 pf[2];
#pragma unroll
          for (int mi = 0; mi < 2; mi++) {
            const int byteR =
                (((mi * 16 + ln) * 64 + ks * 32 + g * 8) * 2) ^ ((ln & 7) << 4);
            pf[mi] = *(const bf16x8*)((const char*)(&Ps[w][0]) + byteR);
          }
#pragma unroll
          for (int nd = 0; nd < 8; nd++) {
            const int row = nd * 16 + ln;
            const int sl = (ks * 4 + g) ^ (row & 7);
            const bf16x8 vf = *(const bf16x8*)(Vst + row * 64 + sl * 8);
#pragma unroll
            for (int mi = 0; mi < 2; mi++)
              oacc[mi][nd] =
                  __builtin_amdgcn_mfma_f32_16x16x32_bf16(vf, pf[mi], oacc[mi][nd], 0, 0, 0);
          }
        }
        __builtin_amdgcn_s_setprio(0);
      }
      __builtin_amdgcn_s_barrier();
    }

    // ---- epilogue
    {
      ushort_t* Ob = O + (size_t)(b * S_ + q0 + w * 32) * E_ + h * D_;
#pragma unroll
      for (int mi = 0; mi < 2; mi++) {
        const float inv = 1.0f / srun[mi];
#pragma unroll
        for (int nd = 0; nd < 8; nd++) {
          const uint_t lo = cvt_pk_bf16(oacc[mi][nd][0] * inv, oacc[mi][nd][1] * inv);
          const uint_t hi = cvt_pk_bf16(oacc[mi][nd][2] * inv, oacc[mi][nd][3] * inv);
          *(uint2*)(Ob + (size_t)(mi * 16 + ln) * E_ + nd * 16 + g * 4) = make_uint2(lo, hi);
        }
      }
    }
  }
#undef STAGE_KV
}

// ---------------------------------------------------------------- launch
extern "C" void kernel_launch(void* const* d_in, const int* in_sizes, int n_in,
                              void* d_out, int out_size, void* d_ws, size_t ws_size,
                              hipStream_t stream) {
  const float* x = (const float*)d_in[0];
  const float* Wq = (const float*)d_in[1];
  const float* bq = (const float*)d_in[2];
  const float* Wk = (const float*)d_in[3];
  const float* bk = (const float*)d_in[4];
  const float* Wv = (const float*)d_in[5];
  const float* bv = (const float*)d_in[6];
  const float* Wo = (const float*)d_in[7];
  const float* bo = (const float*)d_in[8];
  float* out = (float*)d_out;

  ushort_t* ws = (ushort_t*)d_ws;
  const size_t SZ = (size_t)M_ * E_;   // 16,777,216
  const size_t WSZ = (size_t)E_ * E_;  // 4,194,304
  ushort_t* xb = ws;             // x bf16; reused as attention output
  ushort_t* Qb = ws + SZ;
  ushort_t* Kb = ws + 2 * SZ;
  ushort_t* Vtb = ws + 4 * SZ;   // [B][H][D][S], written directly by V-GEMM (MODE 3)
  ushort_t* Wqb = ws + 5 * SZ;   // 4 weights contiguous
  ushort_t* Wkb = Wqb + WSZ;
  ushort_t* Wvb = Wkb + WSZ;
  ushort_t* Wob = Wvb + WSZ;
  float2* tbl = (float2*)(ws + 6 * SZ);  // 1 MB, after weights
  ushort_t* Ob = xb;

  f32_to_bf16<<<2048, 256, 0, stream>>>(x, xb, SZ / 4);
  w4_to_bf16<<<2048, 256, 0, stream>>>(Wq, Wk, Wv, Wo, Wqb);
  rope_table<<<512, 256, 0, stream>>>(tbl);

  gemm8p<2><<<256, 512, 0, stream>>>(xb, Wqb, bq, tbl, 1.0f, Qb);     // Q + RoPE
  gemm8p<2><<<256, 512, 0, stream>>>(xb, Wkb, bk, tbl, 1.0f, Kb);     // K + RoPE
  gemm8p<3><<<256, 512, 0, stream>>>(xb, Wvb, bv, nullptr, 0.f, Vtb); // V, transposed out

  attn_fwd<<<256, 512, 0, stream>>>(Qb, Kb, Vtb, Ob);

  gemm8p<1><<<256, 512, 0, stream>>>(Ob, Wob, bo, nullptr, 0.f, (void*)out);  // O f32
}

// Round 14
// 404.591 us; speedup vs baseline: 1.0094x; 1.0094x over previous
//
#include <hip/hip_runtime.h>
#include <hip/hip_bf16.h>
#include <stdint.h>

#define B_ 4
#define S_ 2048
#define E_ 2048
#define H_ 16
#define D_ 128
#define M_ (B_ * S_)  // 8192 rows

typedef unsigned short ushort_t;
typedef unsigned int uint_t;
typedef __attribute__((ext_vector_type(4))) float f32x4;
typedef __attribute__((ext_vector_type(2))) uint_t u32x2;
typedef __attribute__((ext_vector_type(8))) short bf16x8;

__device__ __forceinline__ ushort_t f2bf(float f) {
  uint_t u = __float_as_uint(f);
  u += 0x7FFFu + ((u >> 16) & 1u);  // RNE
  return (ushort_t)(u >> 16);
}
__device__ __forceinline__ float bf2f(ushort_t h) {
  return __uint_as_float(((uint_t)h) << 16);
}
__device__ __forceinline__ uint_t cvt_pk_bf16(float lo, float hi) {
  uint_t r;
  asm("v_cvt_pk_bf16_f32 %0, %1, %2" : "=v"(r) : "v"(lo), "v"(hi));
  return r;
}
__device__ __forceinline__ float fexp2(float x) {  // bare v_exp_f32 (2^x)
  float r;
  asm("v_exp_f32 %0, %1" : "=v"(r) : "v"(x));
  return r;
}

#define GLOAD_LDS16(gp, lp)                                   \
  __builtin_amdgcn_global_load_lds(                           \
      (__attribute__((address_space(1))) void*)(gp),          \
      (__attribute__((address_space(3))) void*)(lp), 16, 0, 0)

// ---------------------------------------------------------------- converts
__global__ void f32_to_bf16(const float* __restrict__ in, ushort_t* __restrict__ out,
                            size_t n4) {
  const size_t stride = (size_t)gridDim.x * blockDim.x;
  for (size_t i = (size_t)blockIdx.x * blockDim.x + threadIdx.x; i < n4; i += stride) {
    const f32x4 f = __builtin_nontemporal_load((const f32x4*)in + i);
    u32x2 o;
    o[0] = (uint_t)f2bf(f[0]) | ((uint_t)f2bf(f[1]) << 16);
    o[1] = (uint_t)f2bf(f[2]) | ((uint_t)f2bf(f[3]) << 16);
    __builtin_nontemporal_store(o, (u32x2*)out + i);
  }
}

// fused 4-weight convert: dst = 4 contiguous [E][E] bf16 regions
__global__ void w4_to_bf16(const float* __restrict__ w0, const float* __restrict__ w1,
                           const float* __restrict__ w2, const float* __restrict__ w3,
                           ushort_t* __restrict__ out) {
  const size_t n4 = (size_t)E_ * E_;  // total float4 chunks over all 4 weights
  const size_t per = n4 >> 2;         // 2^20 chunks per weight
  const size_t stride = (size_t)gridDim.x * blockDim.x;
  for (size_t c = (size_t)blockIdx.x * blockDim.x + threadIdx.x; c < n4; c += stride) {
    const int wsel = (int)(c / per);
    const size_t off = c - (size_t)wsel * per;
    const float* src = wsel == 0 ? w0 : (wsel == 1 ? w1 : (wsel == 2 ? w2 : w3));
    const f32x4 f = __builtin_nontemporal_load((const f32x4*)src + off);
    u32x2 o;
    o[0] = (uint_t)f2bf(f[0]) | ((uint_t)f2bf(f[1]) << 16);
    o[1] = (uint_t)f2bf(f[2]) | ((uint_t)f2bf(f[3]) << 16);
    __builtin_nontemporal_store(o, (u32x2*)out + c);
  }
}

// ---------------------------------------------------------------- RoPE cos/sin table
__global__ void rope_table(float2* __restrict__ tab) {
  const int i = blockIdx.x * 256 + threadIdx.x;  // grid 512 -> 131072
  const int s = i >> 6, p = i & 63;
  const float inv = exp2f(-0.20762050593046f * (float)p);  // 10000^(-2p/128)
  float sn, cs;
  sincosf((float)s * inv, &sn, &cs);
  tab[i] = make_float2(cs, sn);
}

// ================================================================ 8-phase GEMM (round-8 proven)
#define G8_BARR asm volatile("s_barrier" ::: "memory")
#define G8_VM6 asm volatile("s_waitcnt vmcnt(6)" ::: "memory")
#define G8_VM0 asm volatile("s_waitcnt vmcnt(0)" ::: "memory")
#define G8_LGKM0                                         \
  do {                                                   \
    asm volatile("s_waitcnt lgkmcnt(0)" ::: "memory");   \
    __builtin_amdgcn_sched_barrier(0);                   \
  } while (0)
#define G8_RDB(bp, kk)                                                         \
  _Pragma("unroll") for (int ni = 0; ni < 4; ni++) bfr[ni] =                   \
      *(const bf16x8*)((bp) + bBase + (kk)*16384 + ni * 1024);
#define G8_RDA(bp, kk, mh)                                                     \
  _Pragma("unroll") for (int ai = 0; ai < 4; ai++) af[ai] =                    \
      *(const bf16x8*)((bp) + aBase + (kk)*16384 + (mh)*4096 + ai * 1024);
#define G8_MM(mh)                                                              \
  __builtin_amdgcn_s_setprio(1);                                               \
  _Pragma("unroll") for (int ai = 0; ai < 4; ai++)                             \
      _Pragma("unroll") for (int ni = 0; ni < 4; ni++) acc[(mh)*4 + ai][ni] =  \
          __builtin_amdgcn_mfma_f32_16x16x32_bf16(af[ai], bfr[ni],             \
                                                  acc[(mh)*4 + ai][ni], 0, 0, 0); \
  __builtin_amdgcn_s_setprio(0);

// MODE 0: bf16. MODE 1: f32. MODE 2: bf16 + RoPE(table)*sc.
// MODE 3: bf16 TRANSPOSED V-output (fused transpose_v).
template <int MODE>
__global__ __launch_bounds__(512, 2) void gemm8p(const ushort_t* __restrict__ A,
                                                 const ushort_t* __restrict__ Bw,
                                                 const float* __restrict__ bias,
                                                 const float2* __restrict__ tab,
                                                 const float sc,
                                                 void* __restrict__ Cv) {
  __shared__ __align__(16) char lds[131072];
  const int tid = threadIdx.x;
  const int w = tid >> 6, l = tid & 63, g = l >> 4, ln = l & 15;
  const int wm = w >> 2, wn = w & 3;

  const int flat = blockIdx.x;  // 256 blocks; XCD-chunked bijective swizzle
  const int swz = (flat & 7) * 32 + (flat >> 3);
  const int m0 = (swz >> 3) * 256, n0 = (swz & 7) * 256;

  const ushort_t* Ab = A + (size_t)m0 * E_;
  const ushort_t* Bb = Bw + (size_t)n0 * E_;

  int srcRow[2], srcCc[2];
#pragma unroll
  for (int i = 0; i < 2; i++) {
    const int c = i * 512 + tid;       // chunk 0..1023 of one 16KB slab
    const int r2 = c >> 3;             // row-pair 0..127
    const int j = (c & 7) ^ (r2 & 7);  // inverse chunk-XOR swizzle
    srcRow[i] = 2 * r2 + (j >> 2);
    srcCc[i] = (j & 3) * 8;
  }

  auto STAGE = [&](int t_, int mat, int kk) {
    char* dst = lds + (t_ & 1) * 65536 + mat * 32768 + kk * 16384;
    const ushort_t* src = mat ? Bb : Ab;
#pragma unroll
    for (int i = 0; i < 2; i++)
      GLOAD_LDS16(src + (size_t)srcRow[i] * E_ + t_ * 64 + kk * 32 + srcCc[i],
                  dst + (i * 512 + w * 64) * 16);
  };

  const int rp = ln >> 1;
  const int chunkl = ((((ln & 1) << 2) | g) ^ rp);
  const int aBase = wm * 8192 + rp * 128 + chunkl * 16;
  const int bBase = 32768 + wn * 4096 + rp * 128 + chunkl * 16;

  f32x4 acc[8][4];
#pragma unroll
  for (int mi = 0; mi < 8; mi++)
#pragma unroll
    for (int ni = 0; ni < 4; ni++)
#pragma unroll
      for (int r = 0; r < 4; r++) acc[mi][ni][r] = 0.f;

  // prologue: T0 all 4 slabs, T1 {Bk0, Ak0, Bk1}
  STAGE(0, 1, 0); STAGE(0, 0, 0); STAGE(0, 1, 1); STAGE(0, 0, 1);
  STAGE(1, 1, 0); STAGE(1, 0, 0); STAGE(1, 1, 1);
  G8_VM6; G8_BARR;

  const char* b0 = lds;
  const char* b1 = lds + 65536;
  bf16x8 af[4], bfr[4];

  for (int it = 0; it < 15; ++it) {  // 2 K-tiles per iteration
    const int t2 = 2 * it;
    G8_RDB(b0, 0); G8_RDA(b0, 0, 0); STAGE(t2 + 1, 0, 1); G8_BARR; G8_LGKM0; G8_MM(0); G8_BARR;
    G8_RDA(b0, 0, 1);                STAGE(t2 + 2, 1, 0); G8_BARR; G8_LGKM0; G8_MM(1); G8_BARR;
    G8_RDB(b0, 1); G8_RDA(b0, 1, 0); STAGE(t2 + 2, 0, 0); G8_BARR; G8_LGKM0; G8_MM(0); G8_BARR;
    G8_RDA(b0, 1, 1);                STAGE(t2 + 2, 1, 1); G8_BARR; G8_LGKM0; G8_MM(1); G8_VM6; G8_BARR;
    G8_RDB(b1, 0); G8_RDA(b1, 0, 0); STAGE(t2 + 2, 0, 1); G8_BARR; G8_LGKM0; G8_MM(0); G8_BARR;
    G8_RDA(b1, 0, 1);                STAGE(t2 + 3, 1, 0); G8_BARR; G8_LGKM0; G8_MM(1); G8_BARR;
    G8_RDB(b1, 1); G8_RDA(b1, 1, 0); STAGE(t2 + 3, 0, 0); G8_BARR; G8_LGKM0; G8_MM(0); G8_BARR;
    G8_RDA(b1, 1, 1);                STAGE(t2 + 3, 1, 1); G8_BARR; G8_LGKM0; G8_MM(1); G8_VM6; G8_BARR;
  }
  // tail: T30 (b0), T31 (b1)
  G8_RDB(b0, 0); G8_RDA(b0, 0, 0); STAGE(31, 0, 1); G8_BARR; G8_LGKM0; G8_MM(0); G8_BARR;
  G8_RDA(b0, 0, 1);                                 G8_BARR; G8_LGKM0; G8_MM(1); G8_BARR;
  G8_RDB(b0, 1); G8_RDA(b0, 1, 0);                  G8_BARR; G8_LGKM0; G8_MM(0); G8_BARR;
  G8_RDA(b0, 1, 1);                                 G8_BARR; G8_LGKM0; G8_MM(1); G8_VM0; G8_BARR;
  G8_RDB(b1, 0); G8_RDA(b1, 0, 0);                  G8_BARR; G8_LGKM0; G8_MM(0); G8_BARR;
  G8_RDA(b1, 0, 1);                                 G8_BARR; G8_LGKM0; G8_MM(1); G8_BARR;
  G8_RDB(b1, 1); G8_RDA(b1, 1, 0);                  G8_BARR; G8_LGKM0; G8_MM(0); G8_BARR;
  G8_RDA(b1, 1, 1);                                 G8_BARR; G8_LGKM0; G8_MM(1);

  // ---------------- epilogue
  float bv[4];
#pragma unroll
  for (int ni = 0; ni < 4; ni++) bv[ni] = bias[n0 + wn * 64 + ni * 16 + ln];

  if (MODE == 3) {
    // fused V-transpose: acc -> Ct[col][row] bf16 in LDS (XOR swizzle), then
    // fully-coalesced b128 stores along s.
    G8_BARR;  // all waves past their last LDS read of the main loop
#pragma unroll
    for (int mi = 0; mi < 8; mi++)
#pragma unroll
      for (int ni = 0; ni < 4; ni++) {
        const int col = wn * 64 + ni * 16 + ln;       // local col (d-dim) 0..255
        const int row0 = wm * 128 + mi * 16 + g * 4;  // local row (s-dim) 0..252
        const uint_t lo = cvt_pk_bf16(acc[mi][ni][0] + bv[ni], acc[mi][ni][1] + bv[ni]);
        const uint_t hi = cvt_pk_bf16(acc[mi][ni][2] + bv[ni], acc[mi][ni][3] + bv[ni]);
        const int byte = (col * 512 + row0 * 2) ^ ((col & 7) << 4);
        *(uint2*)(lds + byte) = make_uint2(lo, hi);
      }
    G8_BARR;
    const int bb = m0 >> 11, s0b = m0 & (S_ - 1);
#pragma unroll
    for (int i = 0; i < 16; i++) {
      const int c = i * 512 + tid;
      const int colL = c >> 5, q = c & 31;  // col 0..255, 16B chunk 0..31
      const int byte = (colL * 512 + q * 16) ^ ((colL & 7) << 4);
      const bf16x8 vv = *(const bf16x8*)(lds + byte);
      const int gcol = n0 + colL;
      const int hh = gcol >> 7, d = gcol & 127;
      *(bf16x8*)((ushort_t*)Cv + (((size_t)(bb * H_ + hh) * D_ + d) * S_ + s0b + q * 8)) = vv;
    }
    return;
  }

#pragma unroll
  for (int mi = 0; mi < 8; mi++)
#pragma unroll
    for (int ni = 0; ni < 4; ni++) {
      const int col = n0 + wn * 64 + ni * 16 + ln;
      const int p = (col & 127) >> 1;
      const float sgn = (col & 1) ? 1.f : -1.f;
      const int row0 = m0 + wm * 128 + mi * 16 + g * 4;
#pragma unroll
      for (int r = 0; r < 4; r++) {
        const float v = acc[mi][ni][r] + bv[ni];
        if (MODE == 1) {
          ((float*)Cv)[(size_t)(row0 + r) * E_ + col] = v;
        } else if (MODE == 2) {
          const float partner = __shfl_xor(v, 1);
          const float2 t = tab[((row0 + r) & (S_ - 1)) * 64 + p];
          ((ushort_t*)Cv)[(size_t)(row0 + r) * E_ + col] =
              f2bf((v * t.x + sgn * partner * t.y) * sc);
        } else {
          ((ushort_t*)Cv)[(size_t)(row0 + r) * E_ + col] = f2bf(v);
        }
      }
    }
}

// ---------------------------------------------------------------- flash attention (causal)
// EXACT round-12 best config: QBLK=128, 4 waves, 2 blocks/CU (LDS 80 KB), grid 512,
// XCD-grouped (bh%8), balanced pairs (u,15-u), swapped QK^T, exp2-domain softmax,
// defer-max THR 11.5, counted vmcnt(8).
__global__ __launch_bounds__(256, 2) void attn_fwd(const ushort_t* __restrict__ Q,
                                                   const ushort_t* __restrict__ K,
                                                   const ushort_t* __restrict__ Vt,
                                                   ushort_t* __restrict__ O) {
  const int flat = blockIdx.x;
  const int pair = flat >> 6;   // 0..7
  const int bh = flat & 63;     // XCD = bh%8 for all 8 pairs of this bh
  const int b = bh >> 4, h = bh & 15;
  const int tid = threadIdx.x;
  const int w = tid >> 6, l = tid & 63, g = l >> 4, ln = l & 15;

  __shared__ ushort_t Ks[2][64 * 128];  // 32 KB
  __shared__ ushort_t Vs[2][128 * 64];  // 32 KB
  __shared__ ushort_t Ps[4][32 * 64];   // 16 KB, XOR-swizzled rows

  const ushort_t* Kb = K + (size_t)(b * S_) * E_ + h * D_;
  const ushort_t* Vb = Vt + (size_t)(b * H_ + h) * D_ * S_;
  const float scale2 = 0.12751744528276693f;  // D^-0.5 * log2(e)

#define STAGE_KV(buf, kv0_)                                                      \
  do {                                                                           \
    _Pragma("unroll") for (int i = 0; i < 4; i++) {                              \
      const int c = i * 256 + tid;                                               \
      const int row = c >> 4, sl = c & 15;                                       \
      const int gs = sl ^ (row & 7);                                             \
      GLOAD_LDS16(Kb + (size_t)((kv0_) + row) * E_ + gs * 8,                     \
                  (char*)(&Ks[buf][0]) + (i * 256 + w * 64) * 16);               \
    }                                                                            \
    _Pragma("unroll") for (int i = 0; i < 4; i++) {                              \
      const int c = i * 256 + tid;                                               \
      const int row = c >> 3, sl = c & 7;                                        \
      const int gs = sl ^ (row & 7);                                             \
      GLOAD_LDS16(Vb + (size_t)row * S_ + (kv0_) + gs * 8,                       \
                  (char*)(&Vs[buf][0]) + (i * 256 + w * 64) * 16);               \
    }                                                                            \
  } while (0)

  for (int pass = 0; pass < 2; pass++) {
    const int u = (pass == 0) ? pair : (15 - pair);
    const int q0 = u * 128;
    const int wrow0 = q0 + w * 32;

    bf16x8 qf[2][4];
    {
      const ushort_t* qb = Q + (size_t)(b * S_ + wrow0) * E_ + h * D_;
#pragma unroll
      for (int mi = 0; mi < 2; mi++)
#pragma unroll
        for (int kk = 0; kk < 4; kk++) {
          bf16x8 v = *(const bf16x8*)(qb + (size_t)(mi * 16 + ln) * E_ + kk * 32 + g * 8);
#pragma unroll
          for (int j = 0; j < 8; j++) v[j] = (short)f2bf(bf2f((ushort_t)v[j]) * scale2);
          qf[mi][kk] = v;
        }
    }

    f32x4 oacc[2][8];
#pragma unroll
    for (int mi = 0; mi < 2; mi++)
#pragma unroll
      for (int nd = 0; nd < 8; nd++)
#pragma unroll
        for (int r = 0; r < 4; r++) oacc[mi][nd][r] = 0.f;
    float mrun[2], srun[2];
#pragma unroll
    for (int mi = 0; mi < 2; mi++) {
      mrun[mi] = -__builtin_inff();
      srun[mi] = 0.f;
    }

    const int ntu = 2 * u + 2;
    STAGE_KV(0, 0);

    for (int t = 0; t < ntu; t++) {
      const int kv0 = t * 64;
      const int cur = t & 1;
      if (t + 1 < ntu) {
        STAGE_KV(cur ^ 1, kv0 + 64);
        asm volatile("s_waitcnt vmcnt(8)" ::: "memory");
      } else {
        asm volatile("s_waitcnt vmcnt(0)" ::: "memory");
      }
      __builtin_amdgcn_s_barrier();
      __builtin_amdgcn_sched_barrier(0);

      if (kv0 <= wrow0 + 31) {
        const ushort_t* Kst = &Ks[cur][0];
        const ushort_t* Vst = &Vs[cur][0];
        f32x4 sa[2][4];
#pragma unroll
        for (int mi = 0; mi < 2; mi++)
#pragma unroll
          for (int ni = 0; ni < 4; ni++)
#pragma unroll
            for (int r = 0; r < 4; r++) sa[mi][ni][r] = 0.f;
        __builtin_amdgcn_s_setprio(1);
#pragma unroll
        for (int kk = 0; kk < 4; kk++) {
          bf16x8 kf[4];
#pragma unroll
          for (int ni = 0; ni < 4; ni++) {
            const int row = ni * 16 + ln;
            const int sl = (kk * 4 + g) ^ (row & 7);
            kf[ni] = *(const bf16x8*)(Kst + row * 128 + sl * 8);
          }
#pragma unroll
          for (int mi = 0; mi < 2; mi++)
#pragma unroll
            for (int ni = 0; ni < 4; ni++)
              sa[mi][ni] =
                  __builtin_amdgcn_mfma_f32_16x16x32_bf16(kf[ni], qf[mi][kk], sa[mi][ni], 0, 0, 0);
        }
        __builtin_amdgcn_s_setprio(0);
        if (kv0 + 63 > wrow0) {
#pragma unroll
          for (int mi = 0; mi < 2; mi++) {
            const int lim = wrow0 + mi * 16 + ln - kv0;
#pragma unroll
            for (int ni = 0; ni < 4; ni++)
#pragma unroll
              for (int r = 0; r < 4; r++)
                if (ni * 16 + g * 4 + r > lim) sa[mi][ni][r] = -__builtin_inff();
          }
        }
#pragma unroll
        for (int mi = 0; mi < 2; mi++) {
          float vmax = -__builtin_inff();
#pragma unroll
          for (int ni = 0; ni < 4; ni++)
#pragma unroll
            for (int r = 0; r < 4; r++) vmax = fmaxf(vmax, sa[mi][ni][r]);
          vmax = fmaxf(vmax, __shfl_xor(vmax, 16));
          vmax = fmaxf(vmax, __shfl_xor(vmax, 32));
          if (!__all(vmax - mrun[mi] <= 11.5f)) {  // defer-max (exp2 domain)
            const float mnew = fmaxf(mrun[mi], vmax);
            const float fs = fexp2(mrun[mi] - mnew);
            mrun[mi] = mnew;
            srun[mi] *= fs;
#pragma unroll
            for (int nd = 0; nd < 8; nd++)
#pragma unroll
              for (int r = 0; r < 4; r++) oacc[mi][nd][r] *= fs;
          }
          const float m = mrun[mi];
          float psum = 0.f;
#pragma unroll
          for (int ni = 0; ni < 4; ni++) {
            float p0 = fexp2(sa[mi][ni][0] - m);
            float p1 = fexp2(sa[mi][ni][1] - m);
            float p2 = fexp2(sa[mi][ni][2] - m);
            float p3 = fexp2(sa[mi][ni][3] - m);
            psum += (p0 + p1) + (p2 + p3);
            const int byteW =
                (((mi * 16 + ln) * 64 + ni * 16 + g * 4) * 2) ^ ((ln & 7) << 4);
            *(uint2*)((char*)(&Ps[w][0]) + byteW) =
                make_uint2(cvt_pk_bf16(p0, p1), cvt_pk_bf16(p2, p3));
          }
          psum += __shfl_xor(psum, 16);
          psum += __shfl_xor(psum, 32);
          srun[mi] += psum;
        }
        asm volatile("s_waitcnt lgkmcnt(0)" ::: "memory");
        __builtin_amdgcn_sched_barrier(0);
        __builtin_amdgcn_s_setprio(1);
#pragma unroll
        for (int ks = 0; ks < 2; ks++) {
          bf16x8 pf[2];
#pragma unroll
          for (int mi = 0; mi < 2; mi++) {
            const int byteR =
                (((mi * 16 + ln) * 64 + ks * 32 + g * 8) * 2) ^ ((ln & 7) << 4);
            pf[mi] = *(const bf16x8*)((const char*)(&Ps[w][0]) + byteR);
          }
#pragma unroll
          for (int nd = 0; nd < 8; nd++) {
            const int row = nd * 16 + ln;
            const int sl = (ks * 4 + g) ^ (row & 7);
            const bf16x8 vf = *(const bf16x8*)(Vst + row * 64 + sl * 8);
#pragma unroll
            for (int mi = 0; mi < 2; mi++)
              oacc[mi][nd] =
                  __builtin_amdgcn_mfma_f32_16x16x32_bf16(vf, pf[mi], oacc[mi][nd], 0, 0, 0);
          }
        }
        __builtin_amdgcn_s_setprio(0);
      }
      __builtin_amdgcn_s_barrier();
    }

    // ---- epilogue
    {
      ushort_t* Ob = O + (size_t)(b * S_ + q0 + w * 32) * E_ + h * D_;
#pragma unroll
      for (int mi = 0; mi < 2; mi++) {
        const float inv = 1.0f / srun[mi];
#pragma unroll
        for (int nd = 0; nd < 8; nd++) {
          const uint_t lo = cvt_pk_bf16(oacc[mi][nd][0] * inv, oacc[mi][nd][1] * inv);
          const uint_t hi = cvt_pk_bf16(oacc[mi][nd][2] * inv, oacc[mi][nd][3] * inv);
          *(uint2*)(Ob + (size_t)(mi * 16 + ln) * E_ + nd * 16 + g * 4) = make_uint2(lo, hi);
        }
      }
    }
  }
#undef STAGE_KV
}

// ---------------------------------------------------------------- launch
extern "C" void kernel_launch(void* const* d_in, const int* in_sizes, int n_in,
                              void* d_out, int out_size, void* d_ws, size_t ws_size,
                              hipStream_t stream) {
  const float* x = (const float*)d_in[0];
  const float* Wq = (const float*)d_in[1];
  const float* bq = (const float*)d_in[2];
  const float* Wk = (const float*)d_in[3];
  const float* bk = (const float*)d_in[4];
  const float* Wv = (const float*)d_in[5];
  const float* bv = (const float*)d_in[6];
  const float* Wo = (const float*)d_in[7];
  const float* bo = (const float*)d_in[8];
  float* out = (float*)d_out;

  ushort_t* ws = (ushort_t*)d_ws;
  const size_t SZ = (size_t)M_ * E_;   // 16,777,216
  const size_t WSZ = (size_t)E_ * E_;  // 4,194,304
  ushort_t* xb = ws;             // x bf16; reused as attention output
  ushort_t* Qb = ws + SZ;
  ushort_t* Kb = ws + 2 * SZ;
  ushort_t* Vtb = ws + 4 * SZ;   // [B][H][D][S], written directly by V-GEMM (MODE 3)
  ushort_t* Wqb = ws + 5 * SZ;   // 4 weights contiguous
  ushort_t* Wkb = Wqb + WSZ;
  ushort_t* Wvb = Wkb + WSZ;
  ushort_t* Wob = Wvb + WSZ;
  float2* tbl = (float2*)(ws + 6 * SZ);  // 1 MB, after weights
  ushort_t* Ob = xb;

  f32_to_bf16<<<2048, 256, 0, stream>>>(x, xb, SZ / 4);
  w4_to_bf16<<<2048, 256, 0, stream>>>(Wq, Wk, Wv, Wo, Wqb);
  rope_table<<<512, 256, 0, stream>>>(tbl);

  gemm8p<2><<<256, 512, 0, stream>>>(xb, Wqb, bq, tbl, 1.0f, Qb);     // Q + RoPE
  gemm8p<2><<<256, 512, 0, stream>>>(xb, Wkb, bk, tbl, 1.0f, Kb);     // K + RoPE
  gemm8p<3><<<256, 512, 0, stream>>>(xb, Wvb, bv, nullptr, 0.f, Vtb); // V, transposed out

  attn_fwd<<<512, 256, 0, stream>>>(Qb, Kb, Vtb, Ob);

  gemm8p<1><<<256, 512, 0, stream>>>(Ob, Wob, bo, nullptr, 0.f, (void*)out);  // O f32
}

// Round 15
// 403.397 us; speedup vs baseline: 1.0124x; 1.0030x over previous
//
#include <hip/hip_runtime.h>
#include <hip/hip_bf16.h>
#include <stdint.h>

#define B_ 4
#define S_ 2048
#define E_ 2048
#define H_ 16
#define D_ 128
#define M_ (B_ * S_)  // 8192 rows

typedef unsigned short ushort_t;
typedef unsigned int uint_t;
typedef __attribute__((ext_vector_type(4))) float f32x4;
typedef __attribute__((ext_vector_type(2))) uint_t u32x2;
typedef __attribute__((ext_vector_type(8))) short bf16x8;

__device__ __forceinline__ ushort_t f2bf(float f) {
  uint_t u = __float_as_uint(f);
  u += 0x7FFFu + ((u >> 16) & 1u);  // RNE
  return (ushort_t)(u >> 16);
}
__device__ __forceinline__ float bf2f(ushort_t h) {
  return __uint_as_float(((uint_t)h) << 16);
}
__device__ __forceinline__ uint_t cvt_pk_bf16(float lo, float hi) {
  uint_t r;
  asm("v_cvt_pk_bf16_f32 %0, %1, %2" : "=v"(r) : "v"(lo), "v"(hi));
  return r;
}
__device__ __forceinline__ float fexp2(float x) {  // bare v_exp_f32 (2^x)
  float r;
  asm("v_exp_f32 %0, %1" : "=v"(r) : "v"(x));
  return r;
}

#define GLOAD_LDS16(gp, lp)                                   \
  __builtin_amdgcn_global_load_lds(                           \
      (__attribute__((address_space(1))) void*)(gp),          \
      (__attribute__((address_space(3))) void*)(lp), 16, 0, 0)

// ---------------------------------------------------------------- converts
__global__ void f32_to_bf16(const float* __restrict__ in, ushort_t* __restrict__ out,
                            size_t n4) {
  const size_t stride = (size_t)gridDim.x * blockDim.x;
  for (size_t i = (size_t)blockIdx.x * blockDim.x + threadIdx.x; i < n4; i += stride) {
    const f32x4 f = __builtin_nontemporal_load((const f32x4*)in + i);
    u32x2 o;
    o[0] = (uint_t)f2bf(f[0]) | ((uint_t)f2bf(f[1]) << 16);
    o[1] = (uint_t)f2bf(f[2]) | ((uint_t)f2bf(f[3]) << 16);
    __builtin_nontemporal_store(o, (u32x2*)out + i);
  }
}

// fused 4-weight convert: dst = 4 contiguous [E][E] bf16 regions
__global__ void w4_to_bf16(const float* __restrict__ w0, const float* __restrict__ w1,
                           const float* __restrict__ w2, const float* __restrict__ w3,
                           ushort_t* __restrict__ out) {
  const size_t n4 = (size_t)E_ * E_;  // total float4 chunks over all 4 weights
  const size_t per = n4 >> 2;         // 2^20 chunks per weight
  const size_t stride = (size_t)gridDim.x * blockDim.x;
  for (size_t c = (size_t)blockIdx.x * blockDim.x + threadIdx.x; c < n4; c += stride) {
    const int wsel = (int)(c / per);
    const size_t off = c - (size_t)wsel * per;
    const float* src = wsel == 0 ? w0 : (wsel == 1 ? w1 : (wsel == 2 ? w2 : w3));
    const f32x4 f = __builtin_nontemporal_load((const f32x4*)src + off);
    u32x2 o;
    o[0] = (uint_t)f2bf(f[0]) | ((uint_t)f2bf(f[1]) << 16);
    o[1] = (uint_t)f2bf(f[2]) | ((uint_t)f2bf(f[3]) << 16);
    __builtin_nontemporal_store(o, (u32x2*)out + c);
  }
}

// ---------------------------------------------------------------- RoPE cos/sin table
__global__ void rope_table(float2* __restrict__ tab) {
  const int i = blockIdx.x * 256 + threadIdx.x;  // grid 512 -> 131072
  const int s = i >> 6, p = i & 63;
  const float inv = exp2f(-0.20762050593046f * (float)p);  // 10000^(-2p/128)
  float sn, cs;
  sincosf((float)s * inv, &sn, &cs);
  tab[i] = make_float2(cs, sn);
}

// ================================================================ 8-phase GEMM (round-8 proven)
#define G8_BARR asm volatile("s_barrier" ::: "memory")
#define G8_VM6 asm volatile("s_waitcnt vmcnt(6)" ::: "memory")
#define G8_VM0 asm volatile("s_waitcnt vmcnt(0)" ::: "memory")
#define G8_LGKM0                                         \
  do {                                                   \
    asm volatile("s_waitcnt lgkmcnt(0)" ::: "memory");   \
    __builtin_amdgcn_sched_barrier(0);                   \
  } while (0)
#define G8_RDB(bp, kk)                                                         \
  _Pragma("unroll") for (int ni = 0; ni < 4; ni++) bfr[ni] =                   \
      *(const bf16x8*)((bp) + bBase + (kk)*16384 + ni * 1024);
#define G8_RDA(bp, kk, mh)                                                     \
  _Pragma("unroll") for (int ai = 0; ai < 4; ai++) af[ai] =                    \
      *(const bf16x8*)((bp) + aBase + (kk)*16384 + (mh)*4096 + ai * 1024);
#define G8_MM(mh)                                                              \
  __builtin_amdgcn_s_setprio(1);                                               \
  _Pragma("unroll") for (int ai = 0; ai < 4; ai++)                             \
      _Pragma("unroll") for (int ni = 0; ni < 4; ni++) acc[(mh)*4 + ai][ni] =  \
          __builtin_amdgcn_mfma_f32_16x16x32_bf16(af[ai], bfr[ni],             \
                                                  acc[(mh)*4 + ai][ni], 0, 0, 0); \
  __builtin_amdgcn_s_setprio(0);

// MODE 0: bf16. MODE 1: f32. MODE 2: bf16 + RoPE(table)*sc (sc folds attn scale into Q).
// MODE 3: bf16 TRANSPOSED V-output (fused transpose_v).
template <int MODE>
__global__ __launch_bounds__(512, 2) void gemm8p(const ushort_t* __restrict__ A,
                                                 const ushort_t* __restrict__ Bw,
                                                 const float* __restrict__ bias,
                                                 const float2* __restrict__ tab,
                                                 const float sc,
                                                 void* __restrict__ Cv) {
  __shared__ __align__(16) char lds[131072];
  const int tid = threadIdx.x;
  const int w = tid >> 6, l = tid & 63, g = l >> 4, ln = l & 15;
  const int wm = w >> 2, wn = w & 3;

  const int flat = blockIdx.x;  // 256 blocks; XCD-chunked bijective swizzle
  const int swz = (flat & 7) * 32 + (flat >> 3);
  const int m0 = (swz >> 3) * 256, n0 = (swz & 7) * 256;

  const ushort_t* Ab = A + (size_t)m0 * E_;
  const ushort_t* Bb = Bw + (size_t)n0 * E_;

  int srcRow[2], srcCc[2];
#pragma unroll
  for (int i = 0; i < 2; i++) {
    const int c = i * 512 + tid;       // chunk 0..1023 of one 16KB slab
    const int r2 = c >> 3;             // row-pair 0..127
    const int j = (c & 7) ^ (r2 & 7);  // inverse chunk-XOR swizzle
    srcRow[i] = 2 * r2 + (j >> 2);
    srcCc[i] = (j & 3) * 8;
  }

  auto STAGE = [&](int t_, int mat, int kk) {
    char* dst = lds + (t_ & 1) * 65536 + mat * 32768 + kk * 16384;
    const ushort_t* src = mat ? Bb : Ab;
#pragma unroll
    for (int i = 0; i < 2; i++)
      GLOAD_LDS16(src + (size_t)srcRow[i] * E_ + t_ * 64 + kk * 32 + srcCc[i],
                  dst + (i * 512 + w * 64) * 16);
  };

  const int rp = ln >> 1;
  const int chunkl = ((((ln & 1) << 2) | g) ^ rp);
  const int aBase = wm * 8192 + rp * 128 + chunkl * 16;
  const int bBase = 32768 + wn * 4096 + rp * 128 + chunkl * 16;

  f32x4 acc[8][4];
#pragma unroll
  for (int mi = 0; mi < 8; mi++)
#pragma unroll
    for (int ni = 0; ni < 4; ni++)
#pragma unroll
      for (int r = 0; r < 4; r++) acc[mi][ni][r] = 0.f;

  // prologue: T0 all 4 slabs, T1 {Bk0, Ak0, Bk1}
  STAGE(0, 1, 0); STAGE(0, 0, 0); STAGE(0, 1, 1); STAGE(0, 0, 1);
  STAGE(1, 1, 0); STAGE(1, 0, 0); STAGE(1, 1, 1);
  G8_VM6; G8_BARR;

  const char* b0 = lds;
  const char* b1 = lds + 65536;
  bf16x8 af[4], bfr[4];

  for (int it = 0; it < 15; ++it) {  // 2 K-tiles per iteration
    const int t2 = 2 * it;
    G8_RDB(b0, 0); G8_RDA(b0, 0, 0); STAGE(t2 + 1, 0, 1); G8_BARR; G8_LGKM0; G8_MM(0); G8_BARR;
    G8_RDA(b0, 0, 1);                STAGE(t2 + 2, 1, 0); G8_BARR; G8_LGKM0; G8_MM(1); G8_BARR;
    G8_RDB(b0, 1); G8_RDA(b0, 1, 0); STAGE(t2 + 2, 0, 0); G8_BARR; G8_LGKM0; G8_MM(0); G8_BARR;
    G8_RDA(b0, 1, 1);                STAGE(t2 + 2, 1, 1); G8_BARR; G8_LGKM0; G8_MM(1); G8_VM6; G8_BARR;
    G8_RDB(b1, 0); G8_RDA(b1, 0, 0); STAGE(t2 + 2, 0, 1); G8_BARR; G8_LGKM0; G8_MM(0); G8_BARR;
    G8_RDA(b1, 0, 1);                STAGE(t2 + 3, 1, 0); G8_BARR; G8_LGKM0; G8_MM(1); G8_BARR;
    G8_RDB(b1, 1); G8_RDA(b1, 1, 0); STAGE(t2 + 3, 0, 0); G8_BARR; G8_LGKM0; G8_MM(0); G8_BARR;
    G8_RDA(b1, 1, 1);                STAGE(t2 + 3, 1, 1); G8_BARR; G8_LGKM0; G8_MM(1); G8_VM6; G8_BARR;
  }
  // tail: T30 (b0), T31 (b1)
  G8_RDB(b0, 0); G8_RDA(b0, 0, 0); STAGE(31, 0, 1); G8_BARR; G8_LGKM0; G8_MM(0); G8_BARR;
  G8_RDA(b0, 0, 1);                                 G8_BARR; G8_LGKM0; G8_MM(1); G8_BARR;
  G8_RDB(b0, 1); G8_RDA(b0, 1, 0);                  G8_BARR; G8_LGKM0; G8_MM(0); G8_BARR;
  G8_RDA(b0, 1, 1);                                 G8_BARR; G8_LGKM0; G8_MM(1); G8_VM0; G8_BARR;
  G8_RDB(b1, 0); G8_RDA(b1, 0, 0);                  G8_BARR; G8_LGKM0; G8_MM(0); G8_BARR;
  G8_RDA(b1, 0, 1);                                 G8_BARR; G8_LGKM0; G8_MM(1); G8_BARR;
  G8_RDB(b1, 1); G8_RDA(b1, 1, 0);                  G8_BARR; G8_LGKM0; G8_MM(0); G8_BARR;
  G8_RDA(b1, 1, 1);                                 G8_BARR; G8_LGKM0; G8_MM(1);

  // ---------------- epilogue
  float bv[4];
#pragma unroll
  for (int ni = 0; ni < 4; ni++) bv[ni] = bias[n0 + wn * 64 + ni * 16 + ln];

  if (MODE == 3) {
    // fused V-transpose: acc -> Ct[col][row] bf16 in LDS (XOR swizzle), then
    // fully-coalesced b128 stores along s.
    G8_BARR;  // all waves past their last LDS read of the main loop
#pragma unroll
    for (int mi = 0; mi < 8; mi++)
#pragma unroll
      for (int ni = 0; ni < 4; ni++) {
        const int col = wn * 64 + ni * 16 + ln;       // local col (d-dim) 0..255
        const int row0 = wm * 128 + mi * 16 + g * 4;  // local row (s-dim) 0..252
        const uint_t lo = cvt_pk_bf16(acc[mi][ni][0] + bv[ni], acc[mi][ni][1] + bv[ni]);
        const uint_t hi = cvt_pk_bf16(acc[mi][ni][2] + bv[ni], acc[mi][ni][3] + bv[ni]);
        const int byte = (col * 512 + row0 * 2) ^ ((col & 7) << 4);
        *(uint2*)(lds + byte) = make_uint2(lo, hi);
      }
    G8_BARR;
    const int bb = m0 >> 11, s0b = m0 & (S_ - 1);
#pragma unroll
    for (int i = 0; i < 16; i++) {
      const int c = i * 512 + tid;
      const int colL = c >> 5, q = c & 31;  // col 0..255, 16B chunk 0..31
      const int byte = (colL * 512 + q * 16) ^ ((colL & 7) << 4);
      const bf16x8 vv = *(const bf16x8*)(lds + byte);
      const int gcol = n0 + colL;
      const int hh = gcol >> 7, d = gcol & 127;
      *(bf16x8*)((ushort_t*)Cv + (((size_t)(bb * H_ + hh) * D_ + d) * S_ + s0b + q * 8)) = vv;
    }
    return;
  }

#pragma unroll
  for (int mi = 0; mi < 8; mi++)
#pragma unroll
    for (int ni = 0; ni < 4; ni++) {
      const int col = n0 + wn * 64 + ni * 16 + ln;
      const int p = (col & 127) >> 1;
      const float sgn = (col & 1) ? 1.f : -1.f;
      const int row0 = m0 + wm * 128 + mi * 16 + g * 4;
#pragma unroll
      for (int r = 0; r < 4; r++) {
        const float v = acc[mi][ni][r] + bv[ni];
        if (MODE == 1) {
          ((float*)Cv)[(size_t)(row0 + r) * E_ + col] = v;
        } else if (MODE == 2) {
          const float partner = __shfl_xor(v, 1);
          const float2 t = tab[((row0 + r) & (S_ - 1)) * 64 + p];
          ((ushort_t*)Cv)[(size_t)(row0 + r) * E_ + col] =
              f2bf((v * t.x + sgn * partner * t.y) * sc);
        } else {
          ((ushort_t*)Cv)[(size_t)(row0 + r) * E_ + col] = f2bf(v);
        }
      }
    }
}

// ---------------------------------------------------------------- flash attention (causal)
// Round-12 best config; Q arrives PRE-SCALED by D^-0.5*log2(e) (baked in Q-GEMM).
// QBLK=128, 4 waves, 2 blocks/CU, grid 512, XCD-grouped (bh%8), balanced pairs,
// swapped QK^T, exp2-domain softmax, defer-max THR 11.5, counted vmcnt(8).
__global__ __launch_bounds__(256, 2) void attn_fwd(const ushort_t* __restrict__ Q,
                                                   const ushort_t* __restrict__ K,
                                                   const ushort_t* __restrict__ Vt,
                                                   ushort_t* __restrict__ O) {
  const int flat = blockIdx.x;
  const int pair = flat >> 6;   // 0..7
  const int bh = flat & 63;     // XCD = bh%8 for all 8 pairs of this bh
  const int b = bh >> 4, h = bh & 15;
  const int tid = threadIdx.x;
  const int w = tid >> 6, l = tid & 63, g = l >> 4, ln = l & 15;

  __shared__ ushort_t Ks[2][64 * 128];  // 32 KB
  __shared__ ushort_t Vs[2][128 * 64];  // 32 KB
  __shared__ ushort_t Ps[4][32 * 64];   // 16 KB, XOR-swizzled rows

  const ushort_t* Kb = K + (size_t)(b * S_) * E_ + h * D_;
  const ushort_t* Vb = Vt + (size_t)(b * H_ + h) * D_ * S_;

#define STAGE_KV(buf, kv0_)                                                      \
  do {                                                                           \
    _Pragma("unroll") for (int i = 0; i < 4; i++) {                              \
      const int c = i * 256 + tid;                                               \
      const int row = c >> 4, sl = c & 15;                                       \
      const int gs = sl ^ (row & 7);                                             \
      GLOAD_LDS16(Kb + (size_t)((kv0_) + row) * E_ + gs * 8,                     \
                  (char*)(&Ks[buf][0]) + (i * 256 + w * 64) * 16);               \
    }                                                                            \
    _Pragma("unroll") for (int i = 0; i < 4; i++) {                              \
      const int c = i * 256 + tid;                                               \
      const int row = c >> 3, sl = c & 7;                                        \
      const int gs = sl ^ (row & 7);                                             \
      GLOAD_LDS16(Vb + (size_t)row * S_ + (kv0_) + gs * 8,                       \
                  (char*)(&Vs[buf][0]) + (i * 256 + w * 64) * 16);               \
    }                                                                            \
  } while (0)

  for (int pass = 0; pass < 2; pass++) {
    const int u = (pass == 0) ? pair : (15 - pair);
    const int q0 = u * 128;
    const int wrow0 = q0 + w * 32;

    // Q pre-scaled in the Q-GEMM epilogue -> raw vector copy
    bf16x8 qf[2][4];
    {
      const ushort_t* qb = Q + (size_t)(b * S_ + wrow0) * E_ + h * D_;
#pragma unroll
      for (int mi = 0; mi < 2; mi++)
#pragma unroll
        for (int kk = 0; kk < 4; kk++)
          qf[mi][kk] = *(const bf16x8*)(qb + (size_t)(mi * 16 + ln) * E_ + kk * 32 + g * 8);
    }

    f32x4 oacc[2][8];
#pragma unroll
    for (int mi = 0; mi < 2; mi++)
#pragma unroll
      for (int nd = 0; nd < 8; nd++)
#pragma unroll
        for (int r = 0; r < 4; r++) oacc[mi][nd][r] = 0.f;
    float mrun[2], srun[2];
#pragma unroll
    for (int mi = 0; mi < 2; mi++) {
      mrun[mi] = -__builtin_inff();
      srun[mi] = 0.f;
    }

    const int ntu = 2 * u + 2;
    STAGE_KV(0, 0);

    for (int t = 0; t < ntu; t++) {
      const int kv0 = t * 64;
      const int cur = t & 1;
      if (t + 1 < ntu) {
        STAGE_KV(cur ^ 1, kv0 + 64);
        asm volatile("s_waitcnt vmcnt(8)" ::: "memory");
      } else {
        asm volatile("s_waitcnt vmcnt(0)" ::: "memory");
      }
      __builtin_amdgcn_s_barrier();
      __builtin_amdgcn_sched_barrier(0);

      if (kv0 <= wrow0 + 31) {
        const ushort_t* Kst = &Ks[cur][0];
        const ushort_t* Vst = &Vs[cur][0];
        f32x4 sa[2][4];
#pragma unroll
        for (int mi = 0; mi < 2; mi++)
#pragma unroll
          for (int ni = 0; ni < 4; ni++)
#pragma unroll
            for (int r = 0; r < 4; r++) sa[mi][ni][r] = 0.f;
        __builtin_amdgcn_s_setprio(1);
#pragma unroll
        for (int kk = 0; kk < 4; kk++) {
          bf16x8 kf[4];
#pragma unroll
          for (int ni = 0; ni < 4; ni++) {
            const int row = ni * 16 + ln;
            const int sl = (kk * 4 + g) ^ (row & 7);
            kf[ni] = *(const bf16x8*)(Kst + row * 128 + sl * 8);
          }
#pragma unroll
          for (int mi = 0; mi < 2; mi++)
#pragma unroll
            for (int ni = 0; ni < 4; ni++)
              sa[mi][ni] =
                  __builtin_amdgcn_mfma_f32_16x16x32_bf16(kf[ni], qf[mi][kk], sa[mi][ni], 0, 0, 0);
        }
        __builtin_amdgcn_s_setprio(0);
        if (kv0 + 63 > wrow0) {
#pragma unroll
          for (int mi = 0; mi < 2; mi++) {
            const int lim = wrow0 + mi * 16 + ln - kv0;
#pragma unroll
            for (int ni = 0; ni < 4; ni++)
#pragma unroll
              for (int r = 0; r < 4; r++)
                if (ni * 16 + g * 4 + r > lim) sa[mi][ni][r] = -__builtin_inff();
          }
        }
#pragma unroll
        for (int mi = 0; mi < 2; mi++) {
          // max3-friendly reduction tree (v_max3_f32 fusion)
          float v0 = fmaxf(fmaxf(sa[mi][0][0], sa[mi][0][1]), fmaxf(sa[mi][0][2], sa[mi][0][3]));
          float v1 = fmaxf(fmaxf(sa[mi][1][0], sa[mi][1][1]), fmaxf(sa[mi][1][2], sa[mi][1][3]));
          float v2 = fmaxf(fmaxf(sa[mi][2][0], sa[mi][2][1]), fmaxf(sa[mi][2][2], sa[mi][2][3]));
          float v3 = fmaxf(fmaxf(sa[mi][3][0], sa[mi][3][1]), fmaxf(sa[mi][3][2], sa[mi][3][3]));
          float vmax = fmaxf(fmaxf(v0, v1), fmaxf(v2, v3));
          vmax = fmaxf(vmax, __shfl_xor(vmax, 16));
          vmax = fmaxf(vmax, __shfl_xor(vmax, 32));
          if (!__all(vmax - mrun[mi] <= 11.5f)) {  // defer-max (exp2 domain)
            const float mnew = fmaxf(mrun[mi], vmax);
            const float fs = fexp2(mrun[mi] - mnew);
            mrun[mi] = mnew;
            srun[mi] *= fs;
#pragma unroll
            for (int nd = 0; nd < 8; nd++)
#pragma unroll
              for (int r = 0; r < 4; r++) oacc[mi][nd][r] *= fs;
          }
          const float m = mrun[mi];
          float psum = 0.f;
#pragma unroll
          for (int ni = 0; ni < 4; ni++) {
            float p0 = fexp2(sa[mi][ni][0] - m);
            float p1 = fexp2(sa[mi][ni][1] - m);
            float p2 = fexp2(sa[mi][ni][2] - m);
            float p3 = fexp2(sa[mi][ni][3] - m);
            psum += (p0 + p1) + (p2 + p3);
            const int byteW =
                (((mi * 16 + ln) * 64 + ni * 16 + g * 4) * 2) ^ ((ln & 7) << 4);
            *(uint2*)((char*)(&Ps[w][0]) + byteW) =
                make_uint2(cvt_pk_bf16(p0, p1), cvt_pk_bf16(p2, p3));
          }
          psum += __shfl_xor(psum, 16);
          psum += __shfl_xor(psum, 32);
          srun[mi] += psum;
        }
        asm volatile("s_waitcnt lgkmcnt(0)" ::: "memory");
        __builtin_amdgcn_sched_barrier(0);
        __builtin_amdgcn_s_setprio(1);
#pragma unroll
        for (int ks = 0; ks < 2; ks++) {
          bf16x8 pf[2];
#pragma unroll
          for (int mi = 0; mi < 2; mi++) {
            const int byteR =
                (((mi * 16 + ln) * 64 + ks * 32 + g * 8) * 2) ^ ((ln & 7) << 4);
            pf[mi] = *(const bf16x8*)((const char*)(&Ps[w][0]) + byteR);
          }
#pragma unroll
          for (int nd = 0; nd < 8; nd++) {
            const int row = nd * 16 + ln;
            const int sl = (ks * 4 + g) ^ (row & 7);
            const bf16x8 vf = *(const bf16x8*)(Vst + row * 64 + sl * 8);
#pragma unroll
            for (int mi = 0; mi < 2; mi++)
              oacc[mi][nd] =
                  __builtin_amdgcn_mfma_f32_16x16x32_bf16(vf, pf[mi], oacc[mi][nd], 0, 0, 0);
          }
        }
        __builtin_amdgcn_s_setprio(0);
      }
      __builtin_amdgcn_s_barrier();
    }

    // ---- epilogue
    {
      ushort_t* Ob = O + (size_t)(b * S_ + q0 + w * 32) * E_ + h * D_;
#pragma unroll
      for (int mi = 0; mi < 2; mi++) {
        const float inv = 1.0f / srun[mi];
#pragma unroll
        for (int nd = 0; nd < 8; nd++) {
          const uint_t lo = cvt_pk_bf16(oacc[mi][nd][0] * inv, oacc[mi][nd][1] * inv);
          const uint_t hi = cvt_pk_bf16(oacc[mi][nd][2] * inv, oacc[mi][nd][3] * inv);
          *(uint2*)(Ob + (size_t)(mi * 16 + ln) * E_ + nd * 16 + g * 4) = make_uint2(lo, hi);
        }
      }
    }
  }
#undef STAGE_KV
}

// ---------------------------------------------------------------- launch
extern "C" void kernel_launch(void* const* d_in, const int* in_sizes, int n_in,
                              void* d_out, int out_size, void* d_ws, size_t ws_size,
                              hipStream_t stream) {
  const float* x = (const float*)d_in[0];
  const float* Wq = (const float*)d_in[1];
  const float* bq = (const float*)d_in[2];
  const float* Wk = (const float*)d_in[3];
  const float* bk = (const float*)d_in[4];
  const float* Wv = (const float*)d_in[5];
  const float* bv = (const float*)d_in[6];
  const float* Wo = (const float*)d_in[7];
  const float* bo = (const float*)d_in[8];
  float* out = (float*)d_out;

  ushort_t* ws = (ushort_t*)d_ws;
  const size_t SZ = (size_t)M_ * E_;   // 16,777,216
  const size_t WSZ = (size_t)E_ * E_;  // 4,194,304
  ushort_t* xb = ws;             // x bf16; reused as attention output
  ushort_t* Qb = ws + SZ;
  ushort_t* Kb = ws + 2 * SZ;
  ushort_t* Vtb = ws + 4 * SZ;   // [B][H][D][S], written directly by V-GEMM (MODE 3)
  ushort_t* Wqb = ws + 5 * SZ;   // 4 weights contiguous
  ushort_t* Wkb = Wqb + WSZ;
  ushort_t* Wvb = Wkb + WSZ;
  ushort_t* Wob = Wvb + WSZ;
  float2* tbl = (float2*)(ws + 6 * SZ);  // 1 MB, after weights
  ushort_t* Ob = xb;

  const float scale2 = 0.12751744528276693f;  // D^-0.5 * log2(e), baked into Q

  f32_to_bf16<<<2048, 256, 0, stream>>>(x, xb, SZ / 4);
  w4_to_bf16<<<2048, 256, 0, stream>>>(Wq, Wk, Wv, Wo, Wqb);
  rope_table<<<512, 256, 0, stream>>>(tbl);

  gemm8p<2><<<256, 512, 0, stream>>>(xb, Wqb, bq, tbl, scale2, Qb);   // Q + RoPE*scale
  gemm8p<2><<<256, 512, 0, stream>>>(xb, Wkb, bk, tbl, 1.0f, Kb);     // K + RoPE
  gemm8p<3><<<256, 512, 0, stream>>>(xb, Wvb, bv, nullptr, 0.f, Vtb); // V, transposed out

  attn_fwd<<<512, 256, 0, stream>>>(Qb, Kb, Vtb, Ob);

  gemm8p<1><<<256, 512, 0, stream>>>(Ob, Wob, bo, nullptr, 0.f, (void*)out);  // O f32
}

// Round 16
// 401.675 us; speedup vs baseline: 1.0167x; 1.0043x over previous
//
#include <hip/hip_runtime.h>
#include <hip/hip_bf16.h>
#include <stdint.h>

#define B_ 4
#define S_ 2048
#define E_ 2048
#define H_ 16
#define D_ 128
#define M_ (B_ * S_)  // 8192 rows

typedef unsigned short ushort_t;
typedef unsigned int uint_t;
typedef __attribute__((ext_vector_type(4))) float f32x4;
typedef __attribute__((ext_vector_type(2))) uint_t u32x2;
typedef __attribute__((ext_vector_type(8))) short bf16x8;

__device__ __forceinline__ ushort_t f2bf(float f) {
  uint_t u = __float_as_uint(f);
  u += 0x7FFFu + ((u >> 16) & 1u);  // RNE
  return (ushort_t)(u >> 16);
}
__device__ __forceinline__ float bf2f(ushort_t h) {
  return __uint_as_float(((uint_t)h) << 16);
}
__device__ __forceinline__ uint_t cvt_pk_bf16(float lo, float hi) {
  uint_t r;
  asm("v_cvt_pk_bf16_f32 %0, %1, %2" : "=v"(r) : "v"(lo), "v"(hi));
  return r;
}
__device__ __forceinline__ float fexp2(float x) {  // bare v_exp_f32 (2^x)
  float r;
  asm("v_exp_f32 %0, %1" : "=v"(r) : "v"(x));
  return r;
}

#define GLOAD_LDS16(gp, lp)                                   \
  __builtin_amdgcn_global_load_lds(                           \
      (__attribute__((address_space(1))) void*)(gp),          \
      (__attribute__((address_space(3))) void*)(lp), 16, 0, 0)

// ---------------------------------------------------------------- fused prep:
// blocks [0,2048): x f32->bf16; [2048,4096): 4 weights f32->bf16 (contiguous dst);
// [4096,4608): RoPE cos/sin table. All independent streams of work, one launch.
__global__ void prep(const float* __restrict__ x, const float* __restrict__ w0,
                     const float* __restrict__ w1, const float* __restrict__ w2,
                     const float* __restrict__ w3, ushort_t* __restrict__ xb,
                     ushort_t* __restrict__ wb, float2* __restrict__ tab) {
  const int blk = blockIdx.x;
  const int tid = threadIdx.x;
  if (blk < 2048) {
    const size_t n4 = (size_t)M_ * E_ / 4;
    const size_t stride = (size_t)2048 * 256;
    for (size_t i = (size_t)blk * 256 + tid; i < n4; i += stride) {
      const f32x4 f = __builtin_nontemporal_load((const f32x4*)x + i);
      u32x2 o;
      o[0] = (uint_t)f2bf(f[0]) | ((uint_t)f2bf(f[1]) << 16);
      o[1] = (uint_t)f2bf(f[2]) | ((uint_t)f2bf(f[3]) << 16);
      __builtin_nontemporal_store(o, (u32x2*)xb + i);
    }
  } else if (blk < 4096) {
    const size_t n4 = (size_t)E_ * E_;  // total f32x4 chunks over all 4 weights
    const size_t per = n4 >> 2;
    const size_t stride = (size_t)2048 * 256;
    for (size_t c = (size_t)(blk - 2048) * 256 + tid; c < n4; c += stride) {
      const int wsel = (int)(c / per);
      const size_t off = c - (size_t)wsel * per;
      const float* src = wsel == 0 ? w0 : (wsel == 1 ? w1 : (wsel == 2 ? w2 : w3));
      const f32x4 f = __builtin_nontemporal_load((const f32x4*)src + off);
      u32x2 o;
      o[0] = (uint_t)f2bf(f[0]) | ((uint_t)f2bf(f[1]) << 16);
      o[1] = (uint_t)f2bf(f[2]) | ((uint_t)f2bf(f[3]) << 16);
      __builtin_nontemporal_store(o, (u32x2*)wb + c);
    }
  } else {
    const int i = (blk - 4096) * 256 + tid;  // 131072 entries
    const int s = i >> 6, p = i & 63;
    const float inv = exp2f(-0.20762050593046f * (float)p);  // 10000^(-2p/128)
    float sn, cs;
    sincosf((float)s * inv, &sn, &cs);
    tab[i] = make_float2(cs, sn);
  }
}

// ================================================================ 8-phase GEMM (round-8 proven)
#define G8_BARR asm volatile("s_barrier" ::: "memory")
#define G8_VM6 asm volatile("s_waitcnt vmcnt(6)" ::: "memory")
#define G8_VM0 asm volatile("s_waitcnt vmcnt(0)" ::: "memory")
#define G8_LGKM0                                         \
  do {                                                   \
    asm volatile("s_waitcnt lgkmcnt(0)" ::: "memory");   \
    __builtin_amdgcn_sched_barrier(0);                   \
  } while (0)
#define G8_RDB(bp, kk)                                                         \
  _Pragma("unroll") for (int ni = 0; ni < 4; ni++) bfr[ni] =                   \
      *(const bf16x8*)((bp) + bBase + (kk)*16384 + ni * 1024);
#define G8_RDA(bp, kk, mh)                                                     \
  _Pragma("unroll") for (int ai = 0; ai < 4; ai++) af[ai] =                    \
      *(const bf16x8*)((bp) + aBase + (kk)*16384 + (mh)*4096 + ai * 1024);
#define G8_MM(mh)                                                              \
  __builtin_amdgcn_s_setprio(1);                                               \
  _Pragma("unroll") for (int ai = 0; ai < 4; ai++)                             \
      _Pragma("unroll") for (int ni = 0; ni < 4; ni++) acc[(mh)*4 + ai][ni] =  \
          __builtin_amdgcn_mfma_f32_16x16x32_bf16(af[ai], bfr[ni],             \
                                                  acc[(mh)*4 + ai][ni], 0, 0, 0); \
  __builtin_amdgcn_s_setprio(0);

// MODE 0: bf16. MODE 1: f32. MODE 2: bf16 + RoPE(table)*sc (sc folds attn scale into Q).
// MODE 3: bf16 TRANSPOSED V-output (fused transpose_v).
template <int MODE>
__global__ __launch_bounds__(512, 2) void gemm8p(const ushort_t* __restrict__ A,
                                                 const ushort_t* __restrict__ Bw,
                                                 const float* __restrict__ bias,
                                                 const float2* __restrict__ tab,
                                                 const float sc,
                                                 void* __restrict__ Cv) {
  __shared__ __align__(16) char lds[131072];
  const int tid = threadIdx.x;
  const int w = tid >> 6, l = tid & 63, g = l >> 4, ln = l & 15;
  const int wm = w >> 2, wn = w & 3;

  const int flat = blockIdx.x;  // 256 blocks; XCD-chunked bijective swizzle
  const int swz = (flat & 7) * 32 + (flat >> 3);
  const int m0 = (swz >> 3) * 256, n0 = (swz & 7) * 256;

  const ushort_t* Ab = A + (size_t)m0 * E_;
  const ushort_t* Bb = Bw + (size_t)n0 * E_;

  int srcRow[2], srcCc[2];
#pragma unroll
  for (int i = 0; i < 2; i++) {
    const int c = i * 512 + tid;       // chunk 0..1023 of one 16KB slab
    const int r2 = c >> 3;             // row-pair 0..127
    const int j = (c & 7) ^ (r2 & 7);  // inverse chunk-XOR swizzle
    srcRow[i] = 2 * r2 + (j >> 2);
    srcCc[i] = (j & 3) * 8;
  }

  auto STAGE = [&](int t_, int mat, int kk) {
    char* dst = lds + (t_ & 1) * 65536 + mat * 32768 + kk * 16384;
    const ushort_t* src = mat ? Bb : Ab;
#pragma unroll
    for (int i = 0; i < 2; i++)
      GLOAD_LDS16(src + (size_t)srcRow[i] * E_ + t_ * 64 + kk * 32 + srcCc[i],
                  dst + (i * 512 + w * 64) * 16);
  };

  const int rp = ln >> 1;
  const int chunkl = ((((ln & 1) << 2) | g) ^ rp);
  const int aBase = wm * 8192 + rp * 128 + chunkl * 16;
  const int bBase = 32768 + wn * 4096 + rp * 128 + chunkl * 16;

  f32x4 acc[8][4];
#pragma unroll
  for (int mi = 0; mi < 8; mi++)
#pragma unroll
    for (int ni = 0; ni < 4; ni++)
#pragma unroll
      for (int r = 0; r < 4; r++) acc[mi][ni][r] = 0.f;

  // prologue: T0 all 4 slabs, T1 {Bk0, Ak0, Bk1}
  STAGE(0, 1, 0); STAGE(0, 0, 0); STAGE(0, 1, 1); STAGE(0, 0, 1);
  STAGE(1, 1, 0); STAGE(1, 0, 0); STAGE(1, 1, 1);
  G8_VM6; G8_BARR;

  const char* b0 = lds;
  const char* b1 = lds + 65536;
  bf16x8 af[4], bfr[4];

  for (int it = 0; it < 15; ++it) {  // 2 K-tiles per iteration
    const int t2 = 2 * it;
    G8_RDB(b0, 0); G8_RDA(b0, 0, 0); STAGE(t2 + 1, 0, 1); G8_BARR; G8_LGKM0; G8_MM(0); G8_BARR;
    G8_RDA(b0, 0, 1);                STAGE(t2 + 2, 1, 0); G8_BARR; G8_LGKM0; G8_MM(1); G8_BARR;
    G8_RDB(b0, 1); G8_RDA(b0, 1, 0); STAGE(t2 + 2, 0, 0); G8_BARR; G8_LGKM0; G8_MM(0); G8_BARR;
    G8_RDA(b0, 1, 1);                STAGE(t2 + 2, 1, 1); G8_BARR; G8_LGKM0; G8_MM(1); G8_VM6; G8_BARR;
    G8_RDB(b1, 0); G8_RDA(b1, 0, 0); STAGE(t2 + 2, 0, 1); G8_BARR; G8_LGKM0; G8_MM(0); G8_BARR;
    G8_RDA(b1, 0, 1);                STAGE(t2 + 3, 1, 0); G8_BARR; G8_LGKM0; G8_MM(1); G8_BARR;
    G8_RDB(b1, 1); G8_RDA(b1, 1, 0); STAGE(t2 + 3, 0, 0); G8_BARR; G8_LGKM0; G8_MM(0); G8_BARR;
    G8_RDA(b1, 1, 1);                STAGE(t2 + 3, 1, 1); G8_BARR; G8_LGKM0; G8_MM(1); G8_VM6; G8_BARR;
  }
  // tail: T30 (b0), T31 (b1)
  G8_RDB(b0, 0); G8_RDA(b0, 0, 0); STAGE(31, 0, 1); G8_BARR; G8_LGKM0; G8_MM(0); G8_BARR;
  G8_RDA(b0, 0, 1);                                 G8_BARR; G8_LGKM0; G8_MM(1); G8_BARR;
  G8_RDB(b0, 1); G8_RDA(b0, 1, 0);                  G8_BARR; G8_LGKM0; G8_MM(0); G8_BARR;
  G8_RDA(b0, 1, 1);                                 G8_BARR; G8_LGKM0; G8_MM(1); G8_VM0; G8_BARR;
  G8_RDB(b1, 0); G8_RDA(b1, 0, 0);                  G8_BARR; G8_LGKM0; G8_MM(0); G8_BARR;
  G8_RDA(b1, 0, 1);                                 G8_BARR; G8_LGKM0; G8_MM(1); G8_BARR;
  G8_RDB(b1, 1); G8_RDA(b1, 1, 0);                  G8_BARR; G8_LGKM0; G8_MM(0); G8_BARR;
  G8_RDA(b1, 1, 1);                                 G8_BARR; G8_LGKM0; G8_MM(1);

  // ---------------- epilogue
  float bv[4];
#pragma unroll
  for (int ni = 0; ni < 4; ni++) bv[ni] = bias[n0 + wn * 64 + ni * 16 + ln];

  if (MODE == 3) {
    // fused V-transpose: acc -> Ct[col][row] bf16 in LDS (XOR swizzle), then
    // fully-coalesced b128 stores along s.
    G8_BARR;  // all waves past their last LDS read of the main loop
#pragma unroll
    for (int mi = 0; mi < 8; mi++)
#pragma unroll
      for (int ni = 0; ni < 4; ni++) {
        const int col = wn * 64 + ni * 16 + ln;       // local col (d-dim) 0..255
        const int row0 = wm * 128 + mi * 16 + g * 4;  // local row (s-dim) 0..252
        const uint_t lo = cvt_pk_bf16(acc[mi][ni][0] + bv[ni], acc[mi][ni][1] + bv[ni]);
        const uint_t hi = cvt_pk_bf16(acc[mi][ni][2] + bv[ni], acc[mi][ni][3] + bv[ni]);
        const int byte = (col * 512 + row0 * 2) ^ ((col & 7) << 4);
        *(uint2*)(lds + byte) = make_uint2(lo, hi);
      }
    G8_BARR;
    const int bb = m0 >> 11, s0b = m0 & (S_ - 1);
#pragma unroll
    for (int i = 0; i < 16; i++) {
      const int c = i * 512 + tid;
      const int colL = c >> 5, q = c & 31;  // col 0..255, 16B chunk 0..31
      const int byte = (colL * 512 + q * 16) ^ ((colL & 7) << 4);
      const bf16x8 vv = *(const bf16x8*)(lds + byte);
      const int gcol = n0 + colL;
      const int hh = gcol >> 7, d = gcol & 127;
      *(bf16x8*)((ushort_t*)Cv + (((size_t)(bb * H_ + hh) * D_ + d) * S_ + s0b + q * 8)) = vv;
    }
    return;
  }

#pragma unroll
  for (int mi = 0; mi < 8; mi++)
#pragma unroll
    for (int ni = 0; ni < 4; ni++) {
      const int col = n0 + wn * 64 + ni * 16 + ln;
      const int p = (col & 127) >> 1;
      const float sgn = (col & 1) ? 1.f : -1.f;
      const int row0 = m0 + wm * 128 + mi * 16 + g * 4;
#pragma unroll
      for (int r = 0; r < 4; r++) {
        const float v = acc[mi][ni][r] + bv[ni];
        if (MODE == 1) {
          ((float*)Cv)[(size_t)(row0 + r) * E_ + col] = v;
        } else if (MODE == 2) {
          const float partner = __shfl_xor(v, 1);
          const float2 t = tab[((row0 + r) & (S_ - 1)) * 64 + p];
          ((ushort_t*)Cv)[(size_t)(row0 + r) * E_ + col] =
              f2bf((v * t.x + sgn * partner * t.y) * sc);
        } else {
          ((ushort_t*)Cv)[(size_t)(row0 + r) * E_ + col] = f2bf(v);
        }
      }
    }
}

// ---------------------------------------------------------------- flash attention (causal)
// Round-12 best config; Q arrives PRE-SCALED by D^-0.5*log2(e) (baked in Q-GEMM).
// QBLK=128, 4 waves, 2 blocks/CU, grid 512, XCD-grouped (bh%8), balanced pairs,
// swapped QK^T, exp2-domain softmax, defer-max THR 11.5, counted vmcnt(8).
__global__ __launch_bounds__(256, 2) void attn_fwd(const ushort_t* __restrict__ Q,
                                                   const ushort_t* __restrict__ K,
                                                   const ushort_t* __restrict__ Vt,
                                                   ushort_t* __restrict__ O) {
  const int flat = blockIdx.x;
  const int pair = flat >> 6;   // 0..7
  const int bh = flat & 63;     // XCD = bh%8 for all 8 pairs of this bh
  const int b = bh >> 4, h = bh & 15;
  const int tid = threadIdx.x;
  const int w = tid >> 6, l = tid & 63, g = l >> 4, ln = l & 15;

  __shared__ ushort_t Ks[2][64 * 128];  // 32 KB
  __shared__ ushort_t Vs[2][128 * 64];  // 32 KB
  __shared__ ushort_t Ps[4][32 * 64];   // 16 KB, XOR-swizzled rows

  const ushort_t* Kb = K + (size_t)(b * S_) * E_ + h * D_;
  const ushort_t* Vb = Vt + (size_t)(b * H_ + h) * D_ * S_;

#define STAGE_KV(buf, kv0_)                                                      \
  do {                                                                           \
    _Pragma("unroll") for (int i = 0; i < 4; i++) {                              \
      const int c = i * 256 + tid;                                               \
      const int row = c >> 4, sl = c & 15;                                       \
      const int gs = sl ^ (row & 7);                                             \
      GLOAD_LDS16(Kb + (size_t)((kv0_) + row) * E_ + gs * 8,                     \
                  (char*)(&Ks[buf][0]) + (i * 256 + w * 64) * 16);               \
    }                                                                            \
    _Pragma("unroll") for (int i = 0; i < 4; i++) {                              \
      const int c = i * 256 + tid;                                               \
      const int row = c >> 3, sl = c & 7;                                        \
      const int gs = sl ^ (row & 7);                                             \
      GLOAD_LDS16(Vb + (size_t)row * S_ + (kv0_) + gs * 8,                       \
                  (char*)(&Vs[buf][0]) + (i * 256 + w * 64) * 16);               \
    }                                                                            \
  } while (0)

  for (int pass = 0; pass < 2; pass++) {
    const int u = (pass == 0) ? pair : (15 - pair);
    const int q0 = u * 128;
    const int wrow0 = q0 + w * 32;

    // Q pre-scaled in the Q-GEMM epilogue -> raw vector copy
    bf16x8 qf[2][4];
    {
      const ushort_t* qb = Q + (size_t)(b * S_ + wrow0) * E_ + h * D_;
#pragma unroll
      for (int mi = 0; mi < 2; mi++)
#pragma unroll
        for (int kk = 0; kk < 4; kk++)
          qf[mi][kk] = *(const bf16x8*)(qb + (size_t)(mi * 16 + ln) * E_ + kk * 32 + g * 8);
    }

    f32x4 oacc[2][8];
#pragma unroll
    for (int mi = 0; mi < 2; mi++)
#pragma unroll
      for (int nd = 0; nd < 8; nd++)
#pragma unroll
        for (int r = 0; r < 4; r++) oacc[mi][nd][r] = 0.f;
    float mrun[2], srun[2];
#pragma unroll
    for (int mi = 0; mi < 2; mi++) {
      mrun[mi] = -__builtin_inff();
      srun[mi] = 0.f;
    }

    const int ntu = 2 * u + 2;
    STAGE_KV(0, 0);

    for (int t = 0; t < ntu; t++) {
      const int kv0 = t * 64;
      const int cur = t & 1;
      if (t + 1 < ntu) {
        STAGE_KV(cur ^ 1, kv0 + 64);
        asm volatile("s_waitcnt vmcnt(8)" ::: "memory");
      } else {
        asm volatile("s_waitcnt vmcnt(0)" ::: "memory");
      }
      __builtin_amdgcn_s_barrier();
      __builtin_amdgcn_sched_barrier(0);

      if (kv0 <= wrow0 + 31) {
        const ushort_t* Kst = &Ks[cur][0];
        const ushort_t* Vst = &Vs[cur][0];
        f32x4 sa[2][4];
#pragma unroll
        for (int mi = 0; mi < 2; mi++)
#pragma unroll
          for (int ni = 0; ni < 4; ni++)
#pragma unroll
            for (int r = 0; r < 4; r++) sa[mi][ni][r] = 0.f;
        __builtin_amdgcn_s_setprio(1);
#pragma unroll
        for (int kk = 0; kk < 4; kk++) {
          bf16x8 kf[4];
#pragma unroll
          for (int ni = 0; ni < 4; ni++) {
            const int row = ni * 16 + ln;
            const int sl = (kk * 4 + g) ^ (row & 7);
            kf[ni] = *(const bf16x8*)(Kst + row * 128 + sl * 8);
          }
#pragma unroll
          for (int mi = 0; mi < 2; mi++)
#pragma unroll
            for (int ni = 0; ni < 4; ni++)
              sa[mi][ni] =
                  __builtin_amdgcn_mfma_f32_16x16x32_bf16(kf[ni], qf[mi][kk], sa[mi][ni], 0, 0, 0);
        }
        __builtin_amdgcn_s_setprio(0);
        if (kv0 + 63 > wrow0) {
#pragma unroll
          for (int mi = 0; mi < 2; mi++) {
            const int lim = wrow0 + mi * 16 + ln - kv0;
#pragma unroll
            for (int ni = 0; ni < 4; ni++)
#pragma unroll
              for (int r = 0; r < 4; r++)
                if (ni * 16 + g * 4 + r > lim) sa[mi][ni][r] = -__builtin_inff();
          }
        }
#pragma unroll
        for (int mi = 0; mi < 2; mi++) {
          // max3-friendly reduction tree (v_max3_f32 fusion)
          float v0 = fmaxf(fmaxf(sa[mi][0][0], sa[mi][0][1]), fmaxf(sa[mi][0][2], sa[mi][0][3]));
          float v1 = fmaxf(fmaxf(sa[mi][1][0], sa[mi][1][1]), fmaxf(sa[mi][1][2], sa[mi][1][3]));
          float v2 = fmaxf(fmaxf(sa[mi][2][0], sa[mi][2][1]), fmaxf(sa[mi][2][2], sa[mi][2][3]));
          float v3 = fmaxf(fmaxf(sa[mi][3][0], sa[mi][3][1]), fmaxf(sa[mi][3][2], sa[mi][3][3]));
          float vmax = fmaxf(fmaxf(v0, v1), fmaxf(v2, v3));
          vmax = fmaxf(vmax, __shfl_xor(vmax, 16));
          vmax = fmaxf(vmax, __shfl_xor(vmax, 32));
          if (!__all(vmax - mrun[mi] <= 11.5f)) {  // defer-max (exp2 domain)
            const float mnew = fmaxf(mrun[mi], vmax);
            const float fs = fexp2(mrun[mi] - mnew);
            mrun[mi] = mnew;
            srun[mi] *= fs;
#pragma unroll
            for (int nd = 0; nd < 8; nd++)
#pragma unroll
              for (int r = 0; r < 4; r++) oacc[mi][nd][r] *= fs;
          }
          const float m = mrun[mi];
          float psum = 0.f;
#pragma unroll
          for (int ni = 0; ni < 4; ni++) {
            float p0 = fexp2(sa[mi][ni][0] - m);
            float p1 = fexp2(sa[mi][ni][1] - m);
            float p2 = fexp2(sa[mi][ni][2] - m);
            float p3 = fexp2(sa[mi][ni][3] - m);
            psum += (p0 + p1) + (p2 + p3);
            const int byteW =
                (((mi * 16 + ln) * 64 + ni * 16 + g * 4) * 2) ^ ((ln & 7) << 4);
            *(uint2*)((char*)(&Ps[w][0]) + byteW) =
                make_uint2(cvt_pk_bf16(p0, p1), cvt_pk_bf16(p2, p3));
          }
          psum += __shfl_xor(psum, 16);
          psum += __shfl_xor(psum, 32);
          srun[mi] += psum;
        }
        asm volatile("s_waitcnt lgkmcnt(0)" ::: "memory");
        __builtin_amdgcn_sched_barrier(0);
        __builtin_amdgcn_s_setprio(1);
#pragma unroll
        for (int ks = 0; ks < 2; ks++) {
          bf16x8 pf[2];
#pragma unroll
          for (int mi = 0; mi < 2; mi++) {
            const int byteR =
                (((mi * 16 + ln) * 64 + ks * 32 + g * 8) * 2) ^ ((ln & 7) << 4);
            pf[mi] = *(const bf16x8*)((const char*)(&Ps[w][0]) + byteR);
          }
#pragma unroll
          for (int nd = 0; nd < 8; nd++) {
            const int row = nd * 16 + ln;
            const int sl = (ks * 4 + g) ^ (row & 7);
            const bf16x8 vf = *(const bf16x8*)(Vst + row * 64 + sl * 8);
#pragma unroll
            for (int mi = 0; mi < 2; mi++)
              oacc[mi][nd] =
                  __builtin_amdgcn_mfma_f32_16x16x32_bf16(vf, pf[mi], oacc[mi][nd], 0, 0, 0);
          }
        }
        __builtin_amdgcn_s_setprio(0);
      }
      __builtin_amdgcn_s_barrier();
    }

    // ---- epilogue
    {
      ushort_t* Ob = O + (size_t)(b * S_ + q0 + w * 32) * E_ + h * D_;
#pragma unroll
      for (int mi = 0; mi < 2; mi++) {
        const float inv = 1.0f / srun[mi];
#pragma unroll
        for (int nd = 0; nd < 8; nd++) {
          const uint_t lo = cvt_pk_bf16(oacc[mi][nd][0] * inv, oacc[mi][nd][1] * inv);
          const uint_t hi = cvt_pk_bf16(oacc[mi][nd][2] * inv, oacc[mi][nd][3] * inv);
          *(uint2*)(Ob + (size_t)(mi * 16 + ln) * E_ + nd * 16 + g * 4) = make_uint2(lo, hi);
        }
      }
    }
  }
#undef STAGE_KV
}

// ---------------------------------------------------------------- launch
extern "C" void kernel_launch(void* const* d_in, const int* in_sizes, int n_in,
                              void* d_out, int out_size, void* d_ws, size_t ws_size,
                              hipStream_t stream) {
  const float* x = (const float*)d_in[0];
  const float* Wq = (const float*)d_in[1];
  const float* bq = (const float*)d_in[2];
  const float* Wk = (const float*)d_in[3];
  const float* bk = (const float*)d_in[4];
  const float* Wv = (const float*)d_in[5];
  const float* bv = (const float*)d_in[6];
  const float* Wo = (const float*)d_in[7];
  const float* bo = (const float*)d_in[8];
  float* out = (float*)d_out;

  ushort_t* ws = (ushort_t*)d_ws;
  const size_t SZ = (size_t)M_ * E_;   // 16,777,216
  const size_t WSZ = (size_t)E_ * E_;  // 4,194,304
  ushort_t* xb = ws;             // x bf16; reused as attention output
  ushort_t* Qb = ws + SZ;
  ushort_t* Kb = ws + 2 * SZ;
  ushort_t* Vtb = ws + 4 * SZ;   // [B][H][D][S], written directly by V-GEMM (MODE 3)
  ushort_t* Wqb = ws + 5 * SZ;   // 4 weights contiguous
  ushort_t* Wkb = Wqb + WSZ;
  ushort_t* Wvb = Wkb + WSZ;
  ushort_t* Wob = Wvb + WSZ;
  float2* tbl = (float2*)(ws + 6 * SZ);  // 1 MB, after weights
  ushort_t* Ob = xb;

  const float scale2 = 0.12751744528276693f;  // D^-0.5 * log2(e), baked into Q

  prep<<<4608, 256, 0, stream>>>(x, Wq, Wk, Wv, Wo, xb, Wqb, tbl);

  gemm8p<2><<<256, 512, 0, stream>>>(xb, Wqb, bq, tbl, scale2, Qb);   // Q + RoPE*scale
  gemm8p<2><<<256, 512, 0, stream>>>(xb, Wkb, bk, tbl, 1.0f, Kb);     // K + RoPE
  gemm8p<3><<<256, 512, 0, stream>>>(xb, Wvb, bv, nullptr, 0.f, Vtb); // V, transposed out

  attn_fwd<<<512, 256, 0, stream>>>(Qb, Kb, Vtb, Ob);

  gemm8p<1><<<256, 512, 0, stream>>>(Ob, Wob, bo, nullptr, 0.f, (void*)out);  // O f32
}

// Round 17
// 400.095 us; speedup vs baseline: 1.0208x; 1.0039x over previous
//
#include <hip/hip_runtime.h>
#include <hip/hip_bf16.h>
#include <stdint.h>

#define B_ 4
#define S_ 2048
#define E_ 2048
#define H_ 16
#define D_ 128
#define M_ (B_ * S_)  // 8192 rows

typedef unsigned short ushort_t;
typedef unsigned int uint_t;
typedef __attribute__((ext_vector_type(4))) float f32x4;
typedef __attribute__((ext_vector_type(2))) uint_t u32x2;
typedef __attribute__((ext_vector_type(8))) short bf16x8;

__device__ __forceinline__ ushort_t f2bf(float f) {
  uint_t u = __float_as_uint(f);
  u += 0x7FFFu + ((u >> 16) & 1u);  // RNE
  return (ushort_t)(u >> 16);
}
__device__ __forceinline__ float bf2f(ushort_t h) {
  return __uint_as_float(((uint_t)h) << 16);
}
__device__ __forceinline__ uint_t cvt_pk_bf16(float lo, float hi) {
  uint_t r;
  asm("v_cvt_pk_bf16_f32 %0, %1, %2" : "=v"(r) : "v"(lo), "v"(hi));
  return r;
}
__device__ __forceinline__ float fexp2(float x) {  // bare v_exp_f32 (2^x)
  float r;
  asm("v_exp_f32 %0, %1" : "=v"(r) : "v"(x));
  return r;
}

#define GLOAD_LDS16(gp, lp)                                   \
  __builtin_amdgcn_global_load_lds(                           \
      (__attribute__((address_space(1))) void*)(gp),          \
      (__attribute__((address_space(3))) void*)(lp), 16, 0, 0)

// ---------------------------------------------------------------- fused prep:
// blocks [0,2048): x f32->bf16; [2048,4096): 4 weights f32->bf16 (contiguous dst);
// [4096,4608): RoPE cos/sin table.
__global__ void prep(const float* __restrict__ x, const float* __restrict__ w0,
                     const float* __restrict__ w1, const float* __restrict__ w2,
                     const float* __restrict__ w3, ushort_t* __restrict__ xb,
                     ushort_t* __restrict__ wb, float2* __restrict__ tab) {
  const int blk = blockIdx.x;
  const int tid = threadIdx.x;
  if (blk < 2048) {
    const size_t n4 = (size_t)M_ * E_ / 4;
    const size_t stride = (size_t)2048 * 256;
    for (size_t i = (size_t)blk * 256 + tid; i < n4; i += stride) {
      const f32x4 f = __builtin_nontemporal_load((const f32x4*)x + i);
      u32x2 o;
      o[0] = (uint_t)f2bf(f[0]) | ((uint_t)f2bf(f[1]) << 16);
      o[1] = (uint_t)f2bf(f[2]) | ((uint_t)f2bf(f[3]) << 16);
      __builtin_nontemporal_store(o, (u32x2*)xb + i);
    }
  } else if (blk < 4096) {
    const size_t n4 = (size_t)E_ * E_;
    const size_t per = n4 >> 2;
    const size_t stride = (size_t)2048 * 256;
    for (size_t c = (size_t)(blk - 2048) * 256 + tid; c < n4; c += stride) {
      const int wsel = (int)(c / per);
      const size_t off = c - (size_t)wsel * per;
      const float* src = wsel == 0 ? w0 : (wsel == 1 ? w1 : (wsel == 2 ? w2 : w3));
      const f32x4 f = __builtin_nontemporal_load((const f32x4*)src + off);
      u32x2 o;
      o[0] = (uint_t)f2bf(f[0]) | ((uint_t)f2bf(f[1]) << 16);
      o[1] = (uint_t)f2bf(f[2]) | ((uint_t)f2bf(f[3]) << 16);
      __builtin_nontemporal_store(o, (u32x2*)wb + c);
    }
  } else {
    const int i = (blk - 4096) * 256 + tid;  // 131072 entries
    const int s = i >> 6, p = i & 63;
    const float inv = exp2f(-0.20762050593046f * (float)p);  // 10000^(-2p/128)
    float sn, cs;
    sincosf((float)s * inv, &sn, &cs);
    tab[i] = make_float2(cs, sn);
  }
}

// ================================================================ 8-phase GEMM core
#define G8_BARR asm volatile("s_barrier" ::: "memory")
#define G8_VM6 asm volatile("s_waitcnt vmcnt(6)" ::: "memory")
#define G8_VM0 asm volatile("s_waitcnt vmcnt(0)" ::: "memory")
#define G8_LGKM0                                         \
  do {                                                   \
    asm volatile("s_waitcnt lgkmcnt(0)" ::: "memory");   \
    __builtin_amdgcn_sched_barrier(0);                   \
  } while (0)
#define G8_RDB(bp, kk)                                                         \
  _Pragma("unroll") for (int ni = 0; ni < 4; ni++) bfr[ni] =                   \
      *(const bf16x8*)((bp) + bBase + (kk)*16384 + ni * 1024);
#define G8_RDA(bp, kk, mh)                                                     \
  _Pragma("unroll") for (int ai = 0; ai < 4; ai++) af[ai] =                    \
      *(const bf16x8*)((bp) + aBase + (kk)*16384 + (mh)*4096 + ai * 1024);
#define G8_MM(mh)                                                              \
  __builtin_amdgcn_s_setprio(1);                                               \
  _Pragma("unroll") for (int ai = 0; ai < 4; ai++)                             \
      _Pragma("unroll") for (int ni = 0; ni < 4; ni++) acc[(mh)*4 + ai][ni] =  \
          __builtin_amdgcn_mfma_f32_16x16x32_bf16(af[ai], bfr[ni],             \
                                                  acc[(mh)*4 + ai][ni], 0, 0, 0); \
  __builtin_amdgcn_s_setprio(0);

// Shared main loop (round-8 verified schedule). Declares acc/af/bfr, runs 32 K-tiles.
#define G8_MAINLOOP                                                                          \
  f32x4 acc[8][4];                                                                           \
  _Pragma("unroll") for (int mi = 0; mi < 8; mi++)                                           \
      _Pragma("unroll") for (int ni = 0; ni < 4; ni++)                                       \
          _Pragma("unroll") for (int r = 0; r < 4; r++) acc[mi][ni][r] = 0.f;                \
  STAGE(0, 1, 0); STAGE(0, 0, 0); STAGE(0, 1, 1); STAGE(0, 0, 1);                            \
  STAGE(1, 1, 0); STAGE(1, 0, 0); STAGE(1, 1, 1);                                            \
  G8_VM6; G8_BARR;                                                                           \
  const char* b0 = lds;                                                                      \
  const char* b1 = lds + 65536;                                                              \
  bf16x8 af[4], bfr[4];                                                                      \
  for (int it = 0; it < 15; ++it) {                                                          \
    const int t2 = 2 * it;                                                                   \
    G8_RDB(b0, 0); G8_RDA(b0, 0, 0); STAGE(t2 + 1, 0, 1); G8_BARR; G8_LGKM0; G8_MM(0); G8_BARR; \
    G8_RDA(b0, 0, 1);                STAGE(t2 + 2, 1, 0); G8_BARR; G8_LGKM0; G8_MM(1); G8_BARR; \
    G8_RDB(b0, 1); G8_RDA(b0, 1, 0); STAGE(t2 + 2, 0, 0); G8_BARR; G8_LGKM0; G8_MM(0); G8_BARR; \
    G8_RDA(b0, 1, 1);                STAGE(t2 + 2, 1, 1); G8_BARR; G8_LGKM0; G8_MM(1); G8_VM6; G8_BARR; \
    G8_RDB(b1, 0); G8_RDA(b1, 0, 0); STAGE(t2 + 2, 0, 1); G8_BARR; G8_LGKM0; G8_MM(0); G8_BARR; \
    G8_RDA(b1, 0, 1);                STAGE(t2 + 3, 1, 0); G8_BARR; G8_LGKM0; G8_MM(1); G8_BARR; \
    G8_RDB(b1, 1); G8_RDA(b1, 1, 0); STAGE(t2 + 3, 0, 0); G8_BARR; G8_LGKM0; G8_MM(0); G8_BARR; \
    G8_RDA(b1, 1, 1);                STAGE(t2 + 3, 1, 1); G8_BARR; G8_LGKM0; G8_MM(1); G8_VM6; G8_BARR; \
  }                                                                                          \
  G8_RDB(b0, 0); G8_RDA(b0, 0, 0); STAGE(31, 0, 1); G8_BARR; G8_LGKM0; G8_MM(0); G8_BARR;    \
  G8_RDA(b0, 0, 1);                                 G8_BARR; G8_LGKM0; G8_MM(1); G8_BARR;    \
  G8_RDB(b0, 1); G8_RDA(b0, 1, 0);                  G8_BARR; G8_LGKM0; G8_MM(0); G8_BARR;    \
  G8_RDA(b0, 1, 1);                                 G8_BARR; G8_LGKM0; G8_MM(1); G8_VM0; G8_BARR; \
  G8_RDB(b1, 0); G8_RDA(b1, 0, 0);                  G8_BARR; G8_LGKM0; G8_MM(0); G8_BARR;    \
  G8_RDA(b1, 0, 1);                                 G8_BARR; G8_LGKM0; G8_MM(1); G8_BARR;    \
  G8_RDB(b1, 1); G8_RDA(b1, 1, 0);                  G8_BARR; G8_LGKM0; G8_MM(0); G8_BARR;    \
  G8_RDA(b1, 1, 1);                                 G8_BARR; G8_LGKM0; G8_MM(1);

// ---------------------------------------------------------------- fused QKV (grid 768):
// group = blk>>8 selects {Q: RoPE*scale2, K: RoPE, V: transposed-out}; flat = blk&255
// keeps the PROVEN per-GEMM 256-block geometry (no N-fusion -> no L2 panel thrash).
// Eliminates 2 launch drains; K blocks backfill CUs as Q stragglers retire.
__global__ __launch_bounds__(512, 2) void qkv3(const ushort_t* __restrict__ A,
                                               const ushort_t* __restrict__ W3,
                                               const float* __restrict__ bq,
                                               const float* __restrict__ bk,
                                               const float* __restrict__ bvv,
                                               const float2* __restrict__ tab,
                                               const float scQ,
                                               ushort_t* __restrict__ Qo,
                                               ushort_t* __restrict__ Ko,
                                               ushort_t* __restrict__ Vto) {
  __shared__ __align__(16) char lds[131072];
  const int tid = threadIdx.x;
  const int w = tid >> 6, l = tid & 63, g = l >> 4, ln = l & 15;
  const int wm = w >> 2, wn = w & 3;

  const int group = blockIdx.x >> 8;  // 0:Q 1:K 2:V
  const int flat = blockIdx.x & 255;
  const int swz = (flat & 7) * 32 + (flat >> 3);
  const int m0 = (swz >> 3) * 256, n0 = (swz & 7) * 256;

  const ushort_t* Ab = A + (size_t)m0 * E_;
  const ushort_t* Bb = W3 + (size_t)group * E_ * E_ + (size_t)n0 * E_;

  int srcRow[2], srcCc[2];
#pragma unroll
  for (int i = 0; i < 2; i++) {
    const int c = i * 512 + tid;
    const int r2 = c >> 3;
    const int j = (c & 7) ^ (r2 & 7);
    srcRow[i] = 2 * r2 + (j >> 2);
    srcCc[i] = (j & 3) * 8;
  }

  auto STAGE = [&](int t_, int mat, int kk) {
    char* dst = lds + (t_ & 1) * 65536 + mat * 32768 + kk * 16384;
    const ushort_t* src = mat ? Bb : Ab;
#pragma unroll
    for (int i = 0; i < 2; i++)
      GLOAD_LDS16(src + (size_t)srcRow[i] * E_ + t_ * 64 + kk * 32 + srcCc[i],
                  dst + (i * 512 + w * 64) * 16);
  };

  const int rp = ln >> 1;
  const int chunkl = ((((ln & 1) << 2) | g) ^ rp);
  const int aBase = wm * 8192 + rp * 128 + chunkl * 16;
  const int bBase = 32768 + wn * 4096 + rp * 128 + chunkl * 16;

  G8_MAINLOOP

  // ---------------- epilogue (per-block uniform select)
  const float* bias = group == 0 ? bq : (group == 1 ? bk : bvv);
  float bv[4];
#pragma unroll
  for (int ni = 0; ni < 4; ni++) bv[ni] = bias[n0 + wn * 64 + ni * 16 + ln];

  if (group == 2) {
    // fused V-transpose: acc -> Ct[col][row] bf16 in LDS (XOR swizzle), then
    // fully-coalesced b128 stores along s.
    G8_BARR;
#pragma unroll
    for (int mi = 0; mi < 8; mi++)
#pragma unroll
      for (int ni = 0; ni < 4; ni++) {
        const int col = wn * 64 + ni * 16 + ln;
        const int row0 = wm * 128 + mi * 16 + g * 4;
        const uint_t lo = cvt_pk_bf16(acc[mi][ni][0] + bv[ni], acc[mi][ni][1] + bv[ni]);
        const uint_t hi = cvt_pk_bf16(acc[mi][ni][2] + bv[ni], acc[mi][ni][3] + bv[ni]);
        const int byte = (col * 512 + row0 * 2) ^ ((col & 7) << 4);
        *(uint2*)(lds + byte) = make_uint2(lo, hi);
      }
    G8_BARR;
    const int bb = m0 >> 11, s0b = m0 & (S_ - 1);
#pragma unroll
    for (int i = 0; i < 16; i++) {
      const int c = i * 512 + tid;
      const int colL = c >> 5, q = c & 31;
      const int byte = (colL * 512 + q * 16) ^ ((colL & 7) << 4);
      const bf16x8 vv = *(const bf16x8*)(lds + byte);
      const int gcol = n0 + colL;
      const int hh = gcol >> 7, d = gcol & 127;
      *(bf16x8*)(Vto + (((size_t)(bb * H_ + hh) * D_ + d) * S_ + s0b + q * 8)) = vv;
    }
    return;
  }

  const float sc = (group == 0) ? scQ : 1.0f;
  ushort_t* dst = (group == 0) ? Qo : Ko;
#pragma unroll
  for (int mi = 0; mi < 8; mi++)
#pragma unroll
    for (int ni = 0; ni < 4; ni++) {
      const int col = n0 + wn * 64 + ni * 16 + ln;
      const int p = (col & 127) >> 1;
      const float sgn = (col & 1) ? 1.f : -1.f;
      const int row0 = m0 + wm * 128 + mi * 16 + g * 4;
#pragma unroll
      for (int r = 0; r < 4; r++) {
        const float v = acc[mi][ni][r] + bv[ni];
        const float partner = __shfl_xor(v, 1);
        const float2 t = tab[((row0 + r) & (S_ - 1)) * 64 + p];
        dst[(size_t)(row0 + r) * E_ + col] = f2bf((v * t.x + sgn * partner * t.y) * sc);
      }
    }
}

// ---------------------------------------------------------------- out-proj GEMM (f32 out)
__global__ __launch_bounds__(512, 2) void gemm_out(const ushort_t* __restrict__ A,
                                                   const ushort_t* __restrict__ Bw,
                                                   const float* __restrict__ bias,
                                                   float* __restrict__ Cv) {
  __shared__ __align__(16) char lds[131072];
  const int tid = threadIdx.x;
  const int w = tid >> 6, l = tid & 63, g = l >> 4, ln = l & 15;
  const int wm = w >> 2, wn = w & 3;

  const int flat = blockIdx.x;
  const int swz = (flat & 7) * 32 + (flat >> 3);
  const int m0 = (swz >> 3) * 256, n0 = (swz & 7) * 256;

  const ushort_t* Ab = A + (size_t)m0 * E_;
  const ushort_t* Bb = Bw + (size_t)n0 * E_;

  int srcRow[2], srcCc[2];
#pragma unroll
  for (int i = 0; i < 2; i++) {
    const int c = i * 512 + tid;
    const int r2 = c >> 3;
    const int j = (c & 7) ^ (r2 & 7);
    srcRow[i] = 2 * r2 + (j >> 2);
    srcCc[i] = (j & 3) * 8;
  }

  auto STAGE = [&](int t_, int mat, int kk) {
    char* dst = lds + (t_ & 1) * 65536 + mat * 32768 + kk * 16384;
    const ushort_t* src = mat ? Bb : Ab;
#pragma unroll
    for (int i = 0; i < 2; i++)
      GLOAD_LDS16(src + (size_t)srcRow[i] * E_ + t_ * 64 + kk * 32 + srcCc[i],
                  dst + (i * 512 + w * 64) * 16);
  };

  const int rp = ln >> 1;
  const int chunkl = ((((ln & 1) << 2) | g) ^ rp);
  const int aBase = wm * 8192 + rp * 128 + chunkl * 16;
  const int bBase = 32768 + wn * 4096 + rp * 128 + chunkl * 16;

  G8_MAINLOOP

  float bv[4];
#pragma unroll
  for (int ni = 0; ni < 4; ni++) bv[ni] = bias[n0 + wn * 64 + ni * 16 + ln];
#pragma unroll
  for (int mi = 0; mi < 8; mi++)
#pragma unroll
    for (int ni = 0; ni < 4; ni++) {
      const int col = n0 + wn * 64 + ni * 16 + ln;
      const int row0 = m0 + wm * 128 + mi * 16 + g * 4;
#pragma unroll
      for (int r = 0; r < 4; r++)
        Cv[(size_t)(row0 + r) * E_ + col] = acc[mi][ni][r] + bv[ni];
    }
}

// ---------------------------------------------------------------- flash attention (causal)
// Converged config: QBLK=128, 4 waves, 2 blocks/CU, grid 512, XCD-grouped (bh%8),
// balanced pairs, swapped QK^T, exp2 softmax (Q pre-scaled), defer-max 11.5,
// counted vmcnt(8), max3 reduction tree.
__global__ __launch_bounds__(256, 2) void attn_fwd(const ushort_t* __restrict__ Q,
                                                   const ushort_t* __restrict__ K,
                                                   const ushort_t* __restrict__ Vt,
                                                   ushort_t* __restrict__ O) {
  const int flat = blockIdx.x;
  const int pair = flat >> 6;   // 0..7
  const int bh = flat & 63;     // XCD = bh%8 for all 8 pairs of this bh
  const int b = bh >> 4, h = bh & 15;
  const int tid = threadIdx.x;
  const int w = tid >> 6, l = tid & 63, g = l >> 4, ln = l & 15;

  __shared__ ushort_t Ks[2][64 * 128];  // 32 KB
  __shared__ ushort_t Vs[2][128 * 64];  // 32 KB
  __shared__ ushort_t Ps[4][32 * 64];   // 16 KB, XOR-swizzled rows

  const ushort_t* Kb = K + (size_t)(b * S_) * E_ + h * D_;
  const ushort_t* Vb = Vt + (size_t)(b * H_ + h) * D_ * S_;

#define STAGE_KV(buf, kv0_)                                                      \
  do {                                                                           \
    _Pragma("unroll") for (int i = 0; i < 4; i++) {                              \
      const int c = i * 256 + tid;                                               \
      const int row = c >> 4, sl = c & 15;                                       \
      const int gs = sl ^ (row & 7);                                             \
      GLOAD_LDS16(Kb + (size_t)((kv0_) + row) * E_ + gs * 8,                     \
                  (char*)(&Ks[buf][0]) + (i * 256 + w * 64) * 16);               \
    }                                                                            \
    _Pragma("unroll") for (int i = 0; i < 4; i++) {                              \
      const int c = i * 256 + tid;                                               \
      const int row = c >> 3, sl = c & 7;                                        \
      const int gs = sl ^ (row & 7);                                             \
      GLOAD_LDS16(Vb + (size_t)row * S_ + (kv0_) + gs * 8,                       \
                  (char*)(&Vs[buf][0]) + (i * 256 + w * 64) * 16);               \
    }                                                                            \
  } while (0)

  for (int pass = 0; pass < 2; pass++) {
    const int u = (pass == 0) ? pair : (15 - pair);
    const int q0 = u * 128;
    const int wrow0 = q0 + w * 32;

    bf16x8 qf[2][4];
    {
      const ushort_t* qb = Q + (size_t)(b * S_ + wrow0) * E_ + h * D_;
#pragma unroll
      for (int mi = 0; mi < 2; mi++)
#pragma unroll
        for (int kk = 0; kk < 4; kk++)
          qf[mi][kk] = *(const bf16x8*)(qb + (size_t)(mi * 16 + ln) * E_ + kk * 32 + g * 8);
    }

    f32x4 oacc[2][8];
#pragma unroll
    for (int mi = 0; mi < 2; mi++)
#pragma unroll
      for (int nd = 0; nd < 8; nd++)
#pragma unroll
        for (int r = 0; r < 4; r++) oacc[mi][nd][r] = 0.f;
    float mrun[2], srun[2];
#pragma unroll
    for (int mi = 0; mi < 2; mi++) {
      mrun[mi] = -__builtin_inff();
      srun[mi] = 0.f;
    }

    const int ntu = 2 * u + 2;
    STAGE_KV(0, 0);

    for (int t = 0; t < ntu; t++) {
      const int kv0 = t * 64;
      const int cur = t & 1;
      if (t + 1 < ntu) {
        STAGE_KV(cur ^ 1, kv0 + 64);
        asm volatile("s_waitcnt vmcnt(8)" ::: "memory");
      } else {
        asm volatile("s_waitcnt vmcnt(0)" ::: "memory");
      }
      __builtin_amdgcn_s_barrier();
      __builtin_amdgcn_sched_barrier(0);

      if (kv0 <= wrow0 + 31) {
        const ushort_t* Kst = &Ks[cur][0];
        const ushort_t* Vst = &Vs[cur][0];
        f32x4 sa[2][4];
#pragma unroll
        for (int mi = 0; mi < 2; mi++)
#pragma unroll
          for (int ni = 0; ni < 4; ni++)
#pragma unroll
            for (int r = 0; r < 4; r++) sa[mi][ni][r] = 0.f;
        __builtin_amdgcn_s_setprio(1);
#pragma unroll
        for (int kk = 0; kk < 4; kk++) {
          bf16x8 kf[4];
#pragma unroll
          for (int ni = 0; ni < 4; ni++) {
            const int row = ni * 16 + ln;
            const int sl = (kk * 4 + g) ^ (row & 7);
            kf[ni] = *(const bf16x8*)(Kst + row * 128 + sl * 8);
          }
#pragma unroll
          for (int mi = 0; mi < 2; mi++)
#pragma unroll
            for (int ni = 0; ni < 4; ni++)
              sa[mi][ni] =
                  __builtin_amdgcn_mfma_f32_16x16x32_bf16(kf[ni], qf[mi][kk], sa[mi][ni], 0, 0, 0);
        }
        __builtin_amdgcn_s_setprio(0);
        if (kv0 + 63 > wrow0) {
#pragma unroll
          for (int mi = 0; mi < 2; mi++) {
            const int lim = wrow0 + mi * 16 + ln - kv0;
#pragma unroll
            for (int ni = 0; ni < 4; ni++)
#pragma unroll
              for (int r = 0; r < 4; r++)
                if (ni * 16 + g * 4 + r > lim) sa[mi][ni][r] = -__builtin_inff();
          }
        }
#pragma unroll
        for (int mi = 0; mi < 2; mi++) {
          float v0 = fmaxf(fmaxf(sa[mi][0][0], sa[mi][0][1]), fmaxf(sa[mi][0][2], sa[mi][0][3]));
          float v1 = fmaxf(fmaxf(sa[mi][1][0], sa[mi][1][1]), fmaxf(sa[mi][1][2], sa[mi][1][3]));
          float v2 = fmaxf(fmaxf(sa[mi][2][0], sa[mi][2][1]), fmaxf(sa[mi][2][2], sa[mi][2][3]));
          float v3 = fmaxf(fmaxf(sa[mi][3][0], sa[mi][3][1]), fmaxf(sa[mi][3][2], sa[mi][3][3]));
          float vmax = fmaxf(fmaxf(v0, v1), fmaxf(v2, v3));
          vmax = fmaxf(vmax, __shfl_xor(vmax, 16));
          vmax = fmaxf(vmax, __shfl_xor(vmax, 32));
          if (!__all(vmax - mrun[mi] <= 11.5f)) {  // defer-max (exp2 domain)
            const float mnew = fmaxf(mrun[mi], vmax);
            const float fs = fexp2(mrun[mi] - mnew);
            mrun[mi] = mnew;
            srun[mi] *= fs;
#pragma unroll
            for (int nd = 0; nd < 8; nd++)
#pragma unroll
              for (int r = 0; r < 4; r++) oacc[mi][nd][r] *= fs;
          }
          const float m = mrun[mi];
          float psum = 0.f;
#pragma unroll
          for (int ni = 0; ni < 4; ni++) {
            float p0 = fexp2(sa[mi][ni][0] - m);
            float p1 = fexp2(sa[mi][ni][1] - m);
            float p2 = fexp2(sa[mi][ni][2] - m);
            float p3 = fexp2(sa[mi][ni][3] - m);
            psum += (p0 + p1) + (p2 + p3);
            const int byteW =
                (((mi * 16 + ln) * 64 + ni * 16 + g * 4) * 2) ^ ((ln & 7) << 4);
            *(uint2*)((char*)(&Ps[w][0]) + byteW) =
                make_uint2(cvt_pk_bf16(p0, p1), cvt_pk_bf16(p2, p3));
          }
          psum += __shfl_xor(psum, 16);
          psum += __shfl_xor(psum, 32);
          srun[mi] += psum;
        }
        asm volatile("s_waitcnt lgkmcnt(0)" ::: "memory");
        __builtin_amdgcn_sched_barrier(0);
        __builtin_amdgcn_s_setprio(1);
#pragma unroll
        for (int ks = 0; ks < 2; ks++) {
          bf16x8 pf[2];
#pragma unroll
          for (int mi = 0; mi < 2; mi++) {
            const int byteR =
                (((mi * 16 + ln) * 64 + ks * 32 + g * 8) * 2) ^ ((ln & 7) << 4);
            pf[mi] = *(const bf16x8*)((const char*)(&Ps[w][0]) + byteR);
          }
#pragma unroll
          for (int nd = 0; nd < 8; nd++) {
            const int row = nd * 16 + ln;
            const int sl = (ks * 4 + g) ^ (row & 7);
            const bf16x8 vf = *(const bf16x8*)(Vst + row * 64 + sl * 8);
#pragma unroll
            for (int mi = 0; mi < 2; mi++)
              oacc[mi][nd] =
                  __builtin_amdgcn_mfma_f32_16x16x32_bf16(vf, pf[mi], oacc[mi][nd], 0, 0, 0);
          }
        }
        __builtin_amdgcn_s_setprio(0);
      }
      __builtin_amdgcn_s_barrier();
    }

    // ---- epilogue
    {
      ushort_t* Ob = O + (size_t)(b * S_ + q0 + w * 32) * E_ + h * D_;
#pragma unroll
      for (int mi = 0; mi < 2; mi++) {
        const float inv = 1.0f / srun[mi];
#pragma unroll
        for (int nd = 0; nd < 8; nd++) {
          const uint_t lo = cvt_pk_bf16(oacc[mi][nd][0] * inv, oacc[mi][nd][1] * inv);
          const uint_t hi = cvt_pk_bf16(oacc[mi][nd][2] * inv, oacc[mi][nd][3] * inv);
          *(uint2*)(Ob + (size_t)(mi * 16 + ln) * E_ + nd * 16 + g * 4) = make_uint2(lo, hi);
        }
      }
    }
  }
#undef STAGE_KV
}

// ---------------------------------------------------------------- launch
extern "C" void kernel_launch(void* const* d_in, const int* in_sizes, int n_in,
                              void* d_out, int out_size, void* d_ws, size_t ws_size,
                              hipStream_t stream) {
  const float* x = (const float*)d_in[0];
  const float* Wq = (const float*)d_in[1];
  const float* bq = (const float*)d_in[2];
  const float* Wk = (const float*)d_in[3];
  const float* bk = (const float*)d_in[4];
  const float* Wv = (const float*)d_in[5];
  const float* bv = (const float*)d_in[6];
  const float* Wo = (const float*)d_in[7];
  const float* bo = (const float*)d_in[8];
  float* out = (float*)d_out;

  ushort_t* ws = (ushort_t*)d_ws;
  const size_t SZ = (size_t)M_ * E_;   // 16,777,216
  const size_t WSZ = (size_t)E_ * E_;  // 4,194,304
  ushort_t* xb = ws;             // x bf16; reused as attention output
  ushort_t* Qb = ws + SZ;
  ushort_t* Kb = ws + 2 * SZ;
  ushort_t* Vtb = ws + 4 * SZ;   // [B][H][D][S], written directly by V epilogue
  ushort_t* Wqb = ws + 5 * SZ;   // 4 weights contiguous (Wq, Wk, Wv, Wo)
  ushort_t* Wob = Wqb + 3 * WSZ;
  float2* tbl = (float2*)(ws + 6 * SZ);  // 1 MB, after weights
  ushort_t* Ob = xb;

  const float scale2 = 0.12751744528276693f;  // D^-0.5 * log2(e), baked into Q

  prep<<<4608, 256, 0, stream>>>(x, Wq, Wk, Wv, Wo, xb, Wqb, tbl);

  qkv3<<<768, 512, 0, stream>>>(xb, Wqb, bq, bk, bv, tbl, scale2, Qb, Kb, Vtb);

  attn_fwd<<<512, 256, 0, stream>>>(Qb, Kb, Vtb, Ob);

  gemm_out<<<256, 512, 0, stream>>>(Ob, Wob, bo, out);
}

// Round 18
// 399.912 us; speedup vs baseline: 1.0212x; 1.0005x over previous
//
#include <hip/hip_runtime.h>
#include <hip/hip_bf16.h>
#include <stdint.h>

#define B_ 4
#define S_ 2048
#define E_ 2048
#define H_ 16
#define D_ 128
#define M_ (B_ * S_)  // 8192 rows

typedef unsigned short ushort_t;
typedef unsigned int uint_t;
typedef __attribute__((ext_vector_type(4))) float f32x4;
typedef __attribute__((ext_vector_type(2))) uint_t u32x2;
typedef __attribute__((ext_vector_type(8))) short bf16x8;

__device__ __forceinline__ ushort_t f2bf(float f) {
  uint_t u = __float_as_uint(f);
  u += 0x7FFFu + ((u >> 16) & 1u);  // RNE
  return (ushort_t)(u >> 16);
}
__device__ __forceinline__ float bf2f(ushort_t h) {
  return __uint_as_float(((uint_t)h) << 16);
}
__device__ __forceinline__ uint_t cvt_pk_bf16(float lo, float hi) {
  uint_t r;
  asm("v_cvt_pk_bf16_f32 %0, %1, %2" : "=v"(r) : "v"(lo), "v"(hi));
  return r;
}
__device__ __forceinline__ float fexp2(float x) {  // bare v_exp_f32 (2^x)
  float r;
  asm("v_exp_f32 %0, %1" : "=v"(r) : "v"(x));
  return r;
}

#define GLOAD_LDS16(gp, lp)                                   \
  __builtin_amdgcn_global_load_lds(                           \
      (__attribute__((address_space(1))) void*)(gp),          \
      (__attribute__((address_space(3))) void*)(lp), 16, 0, 0)

// ---------------------------------------------------------------- fused prep:
// blocks [0,2048): x f32->bf16; [2048,4096): 4 weights f32->bf16 (contiguous dst);
// [4096,4608): RoPE cos/sin table.
__global__ void prep(const float* __restrict__ x, const float* __restrict__ w0,
                     const float* __restrict__ w1, const float* __restrict__ w2,
                     const float* __restrict__ w3, ushort_t* __restrict__ xb,
                     ushort_t* __restrict__ wb, float2* __restrict__ tab) {
  const int blk = blockIdx.x;
  const int tid = threadIdx.x;
  if (blk < 2048) {
    const size_t n4 = (size_t)M_ * E_ / 4;
    const size_t stride = (size_t)2048 * 256;
    for (size_t i = (size_t)blk * 256 + tid; i < n4; i += stride) {
      const f32x4 f = __builtin_nontemporal_load((const f32x4*)x + i);
      u32x2 o;
      o[0] = (uint_t)f2bf(f[0]) | ((uint_t)f2bf(f[1]) << 16);
      o[1] = (uint_t)f2bf(f[2]) | ((uint_t)f2bf(f[3]) << 16);
      __builtin_nontemporal_store(o, (u32x2*)xb + i);
    }
  } else if (blk < 4096) {
    const size_t n4 = (size_t)E_ * E_;
    const size_t per = n4 >> 2;
    const size_t stride = (size_t)2048 * 256;
    for (size_t c = (size_t)(blk - 2048) * 256 + tid; c < n4; c += stride) {
      const int wsel = (int)(c / per);
      const size_t off = c - (size_t)wsel * per;
      const float* src = wsel == 0 ? w0 : (wsel == 1 ? w1 : (wsel == 2 ? w2 : w3));
      const f32x4 f = __builtin_nontemporal_load((const f32x4*)src + off);
      u32x2 o;
      o[0] = (uint_t)f2bf(f[0]) | ((uint_t)f2bf(f[1]) << 16);
      o[1] = (uint_t)f2bf(f[2]) | ((uint_t)f2bf(f[3]) << 16);
      __builtin_nontemporal_store(o, (u32x2*)wb + c);
    }
  } else {
    const int i = (blk - 4096) * 256 + tid;  // 131072 entries
    const int s = i >> 6, p = i & 63;
    const float inv = exp2f(-0.20762050593046f * (float)p);  // 10000^(-2p/128)
    float sn, cs;
    sincosf((float)s * inv, &sn, &cs);
    tab[i] = make_float2(cs, sn);
  }
}

// ================================================================ 8-phase GEMM core
#define G8_BARR asm volatile("s_barrier" ::: "memory")
#define G8_VM6 asm volatile("s_waitcnt vmcnt(6)" ::: "memory")
#define G8_VM0 asm volatile("s_waitcnt vmcnt(0)" ::: "memory")
#define G8_LGKM0                                         \
  do {                                                   \
    asm volatile("s_waitcnt lgkmcnt(0)" ::: "memory");   \
    __builtin_amdgcn_sched_barrier(0);                   \
  } while (0)
#define G8_RDB(bp, kk)                                                         \
  _Pragma("unroll") for (int ni = 0; ni < 4; ni++) bfr[ni] =                   \
      *(const bf16x8*)((bp) + bBase + (kk)*16384 + ni * 1024);
#define G8_RDA(bp, kk, mh)                                                     \
  _Pragma("unroll") for (int ai = 0; ai < 4; ai++) af[ai] =                    \
      *(const bf16x8*)((bp) + aBase + (kk)*16384 + (mh)*4096 + ai * 1024);
#define G8_MM(mh)                                                              \
  __builtin_amdgcn_s_setprio(1);                                               \
  _Pragma("unroll") for (int ai = 0; ai < 4; ai++)                             \
      _Pragma("unroll") for (int ni = 0; ni < 4; ni++) acc[(mh)*4 + ai][ni] =  \
          __builtin_amdgcn_mfma_f32_16x16x32_bf16(af[ai], bfr[ni],             \
                                                  acc[(mh)*4 + ai][ni], 0, 0, 0); \
  __builtin_amdgcn_s_setprio(0);

// Shared main loop (round-8 verified schedule). Declares acc/af/bfr, runs 32 K-tiles.
#define G8_MAINLOOP                                                                          \
  f32x4 acc[8][4];                                                                           \
  _Pragma("unroll") for (int mi = 0; mi < 8; mi++)                                           \
      _Pragma("unroll") for (int ni = 0; ni < 4; ni++)                                       \
          _Pragma("unroll") for (int r = 0; r < 4; r++) acc[mi][ni][r] = 0.f;                \
  STAGE(0, 1, 0); STAGE(0, 0, 0); STAGE(0, 1, 1); STAGE(0, 0, 1);                            \
  STAGE(1, 1, 0); STAGE(1, 0, 0); STAGE(1, 1, 1);                                            \
  G8_VM6; G8_BARR;                                                                           \
  const char* b0 = lds;                                                                      \
  const char* b1 = lds + 65536;                                                              \
  bf16x8 af[4], bfr[4];                                                                      \
  for (int it = 0; it < 15; ++it) {                                                          \
    const int t2 = 2 * it;                                                                   \
    G8_RDB(b0, 0); G8_RDA(b0, 0, 0); STAGE(t2 + 1, 0, 1); G8_BARR; G8_LGKM0; G8_MM(0); G8_BARR; \
    G8_RDA(b0, 0, 1);                STAGE(t2 + 2, 1, 0); G8_BARR; G8_LGKM0; G8_MM(1); G8_BARR; \
    G8_RDB(b0, 1); G8_RDA(b0, 1, 0); STAGE(t2 + 2, 0, 0); G8_BARR; G8_LGKM0; G8_MM(0); G8_BARR; \
    G8_RDA(b0, 1, 1);                STAGE(t2 + 2, 1, 1); G8_BARR; G8_LGKM0; G8_MM(1); G8_VM6; G8_BARR; \
    G8_RDB(b1, 0); G8_RDA(b1, 0, 0); STAGE(t2 + 2, 0, 1); G8_BARR; G8_LGKM0; G8_MM(0); G8_BARR; \
    G8_RDA(b1, 0, 1);                STAGE(t2 + 3, 1, 0); G8_BARR; G8_LGKM0; G8_MM(1); G8_BARR; \
    G8_RDB(b1, 1); G8_RDA(b1, 1, 0); STAGE(t2 + 3, 0, 0); G8_BARR; G8_LGKM0; G8_MM(0); G8_BARR; \
    G8_RDA(b1, 1, 1);                STAGE(t2 + 3, 1, 1); G8_BARR; G8_LGKM0; G8_MM(1); G8_VM6; G8_BARR; \
  }                                                                                          \
  G8_RDB(b0, 0); G8_RDA(b0, 0, 0); STAGE(31, 0, 1); G8_BARR; G8_LGKM0; G8_MM(0); G8_BARR;    \
  G8_RDA(b0, 0, 1);                                 G8_BARR; G8_LGKM0; G8_MM(1); G8_BARR;    \
  G8_RDB(b0, 1); G8_RDA(b0, 1, 0);                  G8_BARR; G8_LGKM0; G8_MM(0); G8_BARR;    \
  G8_RDA(b0, 1, 1);                                 G8_BARR; G8_LGKM0; G8_MM(1); G8_VM0; G8_BARR; \
  G8_RDB(b1, 0); G8_RDA(b1, 0, 0);                  G8_BARR; G8_LGKM0; G8_MM(0); G8_BARR;    \
  G8_RDA(b1, 0, 1);                                 G8_BARR; G8_LGKM0; G8_MM(1); G8_BARR;    \
  G8_RDB(b1, 1); G8_RDA(b1, 1, 0);                  G8_BARR; G8_LGKM0; G8_MM(0); G8_BARR;    \
  G8_RDA(b1, 1, 1);                                 G8_BARR; G8_LGKM0; G8_MM(1);

// ---------------------------------------------------------------- fused QKV (grid 768):
// group: V dispatched FIRST (expensive transposed epilogue off the tail), then Q, K.
// flat = blk&255 keeps the proven per-GEMM 256-block geometry (no N-fusion).
__global__ __launch_bounds__(512, 2) void qkv3(const ushort_t* __restrict__ A,
                                               const ushort_t* __restrict__ W3,
                                               const float* __restrict__ bq,
                                               const float* __restrict__ bk,
                                               const float* __restrict__ bvv,
                                               const float2* __restrict__ tab,
                                               const float scQ,
                                               ushort_t* __restrict__ Qo,
                                               ushort_t* __restrict__ Ko,
                                               ushort_t* __restrict__ Vto) {
  __shared__ __align__(16) char lds[131072];
  const int tid = threadIdx.x;
  const int w = tid >> 6, l = tid & 63, g = l >> 4, ln = l & 15;
  const int wm = w >> 2, wn = w & 3;

  const int group = 2 - (blockIdx.x >> 8);  // blocks 0-255: V; 256-511: K; 512-767: Q
  const int flat = blockIdx.x & 255;
  const int swz = (flat & 7) * 32 + (flat >> 3);
  const int m0 = (swz >> 3) * 256, n0 = (swz & 7) * 256;

  const ushort_t* Ab = A + (size_t)m0 * E_;
  const ushort_t* Bb = W3 + (size_t)group * E_ * E_ + (size_t)n0 * E_;

  int srcRow[2], srcCc[2];
#pragma unroll
  for (int i = 0; i < 2; i++) {
    const int c = i * 512 + tid;
    const int r2 = c >> 3;
    const int j = (c & 7) ^ (r2 & 7);
    srcRow[i] = 2 * r2 + (j >> 2);
    srcCc[i] = (j & 3) * 8;
  }

  auto STAGE = [&](int t_, int mat, int kk) {
    char* dst = lds + (t_ & 1) * 65536 + mat * 32768 + kk * 16384;
    const ushort_t* src = mat ? Bb : Ab;
#pragma unroll
    for (int i = 0; i < 2; i++)
      GLOAD_LDS16(src + (size_t)srcRow[i] * E_ + t_ * 64 + kk * 32 + srcCc[i],
                  dst + (i * 512 + w * 64) * 16);
  };

  const int rp = ln >> 1;
  const int chunkl = ((((ln & 1) << 2) | g) ^ rp);
  const int aBase = wm * 8192 + rp * 128 + chunkl * 16;
  const int bBase = 32768 + wn * 4096 + rp * 128 + chunkl * 16;

  G8_MAINLOOP

  // ---------------- epilogue (per-block uniform select)
  const float* bias = group == 0 ? bq : (group == 1 ? bk : bvv);
  float bv[4];
#pragma unroll
  for (int ni = 0; ni < 4; ni++) bv[ni] = bias[n0 + wn * 64 + ni * 16 + ln];

  if (group == 2) {
    // fused V-transpose: acc -> Ct[col][row] bf16 in LDS (XOR swizzle), then
    // fully-coalesced b128 stores along s.
    G8_BARR;
#pragma unroll
    for (int mi = 0; mi < 8; mi++)
#pragma unroll
      for (int ni = 0; ni < 4; ni++) {
        const int col = wn * 64 + ni * 16 + ln;
        const int row0 = wm * 128 + mi * 16 + g * 4;
        const uint_t lo = cvt_pk_bf16(acc[mi][ni][0] + bv[ni], acc[mi][ni][1] + bv[ni]);
        const uint_t hi = cvt_pk_bf16(acc[mi][ni][2] + bv[ni], acc[mi][ni][3] + bv[ni]);
        const int byte = (col * 512 + row0 * 2) ^ ((col & 7) << 4);
        *(uint2*)(lds + byte) = make_uint2(lo, hi);
      }
    G8_BARR;
    const int bb = m0 >> 11, s0b = m0 & (S_ - 1);
#pragma unroll
    for (int i = 0; i < 16; i++) {
      const int c = i * 512 + tid;
      const int colL = c >> 5, q = c & 31;
      const int byte = (colL * 512 + q * 16) ^ ((colL & 7) << 4);
      const bf16x8 vv = *(const bf16x8*)(lds + byte);
      const int gcol = n0 + colL;
      const int hh = gcol >> 7, d = gcol & 127;
      *(bf16x8*)(Vto + (((size_t)(bb * H_ + hh) * D_ + d) * S_ + s0b + q * 8)) = vv;
    }
    return;
  }

  const float sc = (group == 0) ? scQ : 1.0f;
  ushort_t* dst = (group == 0) ? Qo : Ko;
#pragma unroll
  for (int mi = 0; mi < 8; mi++)
#pragma unroll
    for (int ni = 0; ni < 4; ni++) {
      const int col = n0 + wn * 64 + ni * 16 + ln;
      const int p = (col & 127) >> 1;
      const float sgn = (col & 1) ? 1.f : -1.f;
      const int row0 = m0 + wm * 128 + mi * 16 + g * 4;
#pragma unroll
      for (int r = 0; r < 4; r++) {
        const float v = acc[mi][ni][r] + bv[ni];
        const float partner = __shfl_xor(v, 1);
        const float2 t = tab[((row0 + r) & (S_ - 1)) * 64 + p];
        dst[(size_t)(row0 + r) * E_ + col] = f2bf((v * t.x + sgn * partner * t.y) * sc);
      }
    }
}

// ---------------------------------------------------------------- out-proj GEMM (f32 out)
__global__ __launch_bounds__(512, 2) void gemm_out(const ushort_t* __restrict__ A,
                                                   const ushort_t* __restrict__ Bw,
                                                   const float* __restrict__ bias,
                                                   float* __restrict__ Cv) {
  __shared__ __align__(16) char lds[131072];
  const int tid = threadIdx.x;
  const int w = tid >> 6, l = tid & 63, g = l >> 4, ln = l & 15;
  const int wm = w >> 2, wn = w & 3;

  const int flat = blockIdx.x;
  const int swz = (flat & 7) * 32 + (flat >> 3);
  const int m0 = (swz >> 3) * 256, n0 = (swz & 7) * 256;

  const ushort_t* Ab = A + (size_t)m0 * E_;
  const ushort_t* Bb = Bw + (size_t)n0 * E_;

  int srcRow[2], srcCc[2];
#pragma unroll
  for (int i = 0; i < 2; i++) {
    const int c = i * 512 + tid;
    const int r2 = c >> 3;
    const int j = (c & 7) ^ (r2 & 7);
    srcRow[i] = 2 * r2 + (j >> 2);
    srcCc[i] = (j & 3) * 8;
  }

  auto STAGE = [&](int t_, int mat, int kk) {
    char* dst = lds + (t_ & 1) * 65536 + mat * 32768 + kk * 16384;
    const ushort_t* src = mat ? Bb : Ab;
#pragma unroll
    for (int i = 0; i < 2; i++)
      GLOAD_LDS16(src + (size_t)srcRow[i] * E_ + t_ * 64 + kk * 32 + srcCc[i],
                  dst + (i * 512 + w * 64) * 16);
  };

  const int rp = ln >> 1;
  const int chunkl = ((((ln & 1) << 2) | g) ^ rp);
  const int aBase = wm * 8192 + rp * 128 + chunkl * 16;
  const int bBase = 32768 + wn * 4096 + rp * 128 + chunkl * 16;

  G8_MAINLOOP

  float bv[4];
#pragma unroll
  for (int ni = 0; ni < 4; ni++) bv[ni] = bias[n0 + wn * 64 + ni * 16 + ln];
#pragma unroll
  for (int mi = 0; mi < 8; mi++)
#pragma unroll
    for (int ni = 0; ni < 4; ni++) {
      const int col = n0 + wn * 64 + ni * 16 + ln;
      const int row0 = m0 + wm * 128 + mi * 16 + g * 4;
#pragma unroll
      for (int r = 0; r < 4; r++)
        Cv[(size_t)(row0 + r) * E_ + col] = acc[mi][ni][r] + bv[ni];
    }
}

// ---------------------------------------------------------------- flash attention (causal)
// Converged config: QBLK=128, 4 waves, 2 blocks/CU, grid 512, XCD-grouped (bh%8),
// balanced pairs, swapped QK^T, exp2 softmax (Q pre-scaled), defer-max 11.5,
// counted vmcnt(8), max3 reduction tree.
__global__ __launch_bounds__(256, 2) void attn_fwd(const ushort_t* __restrict__ Q,
                                                   const ushort_t* __restrict__ K,
                                                   const ushort_t* __restrict__ Vt,
                                                   ushort_t* __restrict__ O) {
  const int flat = blockIdx.x;
  const int pair = flat >> 6;   // 0..7
  const int bh = flat & 63;     // XCD = bh%8 for all 8 pairs of this bh
  const int b = bh >> 4, h = bh & 15;
  const int tid = threadIdx.x;
  const int w = tid >> 6, l = tid & 63, g = l >> 4, ln = l & 15;

  __shared__ ushort_t Ks[2][64 * 128];  // 32 KB
  __shared__ ushort_t Vs[2][128 * 64];  // 32 KB
  __shared__ ushort_t Ps[4][32 * 64];   // 16 KB, XOR-swizzled rows

  const ushort_t* Kb = K + (size_t)(b * S_) * E_ + h * D_;
  const ushort_t* Vb = Vt + (size_t)(b * H_ + h) * D_ * S_;

#define STAGE_KV(buf, kv0_)                                                      \
  do {                                                                           \
    _Pragma("unroll") for (int i = 0; i < 4; i++) {                              \
      const int c = i * 256 + tid;                                               \
      const int row = c >> 4, sl = c & 15;                                       \
      const int gs = sl ^ (row & 7);                                             \
      GLOAD_LDS16(Kb + (size_t)((kv0_) + row) * E_ + gs * 8,                     \
                  (char*)(&Ks[buf][0]) + (i * 256 + w * 64) * 16);               \
    }                                                                            \
    _Pragma("unroll") for (int i = 0; i < 4; i++) {                              \
      const int c = i * 256 + tid;                                               \
      const int row = c >> 3, sl = c & 7;                                        \
      const int gs = sl ^ (row & 7);                                             \
      GLOAD_LDS16(Vb + (size_t)row * S_ + (kv0_) + gs * 8,                       \
                  (char*)(&Vs[buf][0]) + (i * 256 + w * 64) * 16);               \
    }                                                                            \
  } while (0)

  for (int pass = 0; pass < 2; pass++) {
    const int u = (pass == 0) ? pair : (15 - pair);
    const int q0 = u * 128;
    const int wrow0 = q0 + w * 32;

    bf16x8 qf[2][4];
    {
      const ushort_t* qb = Q + (size_t)(b * S_ + wrow0) * E_ + h * D_;
#pragma unroll
      for (int mi = 0; mi < 2; mi++)
#pragma unroll
        for (int kk = 0; kk < 4; kk++)
          qf[mi][kk] = *(const bf16x8*)(qb + (size_t)(mi * 16 + ln) * E_ + kk * 32 + g * 8);
    }

    f32x4 oacc[2][8];
#pragma unroll
    for (int mi = 0; mi < 2; mi++)
#pragma unroll
      for (int nd = 0; nd < 8; nd++)
#pragma unroll
        for (int r = 0; r < 4; r++) oacc[mi][nd][r] = 0.f;
    float mrun[2], srun[2];
#pragma unroll
    for (int mi = 0; mi < 2; mi++) {
      mrun[mi] = -__builtin_inff();
      srun[mi] = 0.f;
    }

    const int ntu = 2 * u + 2;
    STAGE_KV(0, 0);

    for (int t = 0; t < ntu; t++) {
      const int kv0 = t * 64;
      const int cur = t & 1;
      if (t + 1 < ntu) {
        STAGE_KV(cur ^ 1, kv0 + 64);
        asm volatile("s_waitcnt vmcnt(8)" ::: "memory");
      } else {
        asm volatile("s_waitcnt vmcnt(0)" ::: "memory");
      }
      __builtin_amdgcn_s_barrier();
      __builtin_amdgcn_sched_barrier(0);

      if (kv0 <= wrow0 + 31) {
        const ushort_t* Kst = &Ks[cur][0];
        const ushort_t* Vst = &Vs[cur][0];
        f32x4 sa[2][4];
#pragma unroll
        for (int mi = 0; mi < 2; mi++)
#pragma unroll
          for (int ni = 0; ni < 4; ni++)
#pragma unroll
            for (int r = 0; r < 4; r++) sa[mi][ni][r] = 0.f;
        __builtin_amdgcn_s_setprio(1);
#pragma unroll
        for (int kk = 0; kk < 4; kk++) {
          bf16x8 kf[4];
#pragma unroll
          for (int ni = 0; ni < 4; ni++) {
            const int row = ni * 16 + ln;
            const int sl = (kk * 4 + g) ^ (row & 7);
            kf[ni] = *(const bf16x8*)(Kst + row * 128 + sl * 8);
          }
#pragma unroll
          for (int mi = 0; mi < 2; mi++)
#pragma unroll
            for (int ni = 0; ni < 4; ni++)
              sa[mi][ni] =
                  __builtin_amdgcn_mfma_f32_16x16x32_bf16(kf[ni], qf[mi][kk], sa[mi][ni], 0, 0, 0);
        }
        __builtin_amdgcn_s_setprio(0);
        if (kv0 + 63 > wrow0) {
#pragma unroll
          for (int mi = 0; mi < 2; mi++) {
            const int lim = wrow0 + mi * 16 + ln - kv0;
#pragma unroll
            for (int ni = 0; ni < 4; ni++)
#pragma unroll
              for (int r = 0; r < 4; r++)
                if (ni * 16 + g * 4 + r > lim) sa[mi][ni][r] = -__builtin_inff();
          }
        }
#pragma unroll
        for (int mi = 0; mi < 2; mi++) {
          float v0 = fmaxf(fmaxf(sa[mi][0][0], sa[mi][0][1]), fmaxf(sa[mi][0][2], sa[mi][0][3]));
          float v1 = fmaxf(fmaxf(sa[mi][1][0], sa[mi][1][1]), fmaxf(sa[mi][1][2], sa[mi][1][3]));
          float v2 = fmaxf(fmaxf(sa[mi][2][0], sa[mi][2][1]), fmaxf(sa[mi][2][2], sa[mi][2][3]));
          float v3 = fmaxf(fmaxf(sa[mi][3][0], sa[mi][3][1]), fmaxf(sa[mi][3][2], sa[mi][3][3]));
          float vmax = fmaxf(fmaxf(v0, v1), fmaxf(v2, v3));
          vmax = fmaxf(vmax, __shfl_xor(vmax, 16));
          vmax = fmaxf(vmax, __shfl_xor(vmax, 32));
          if (!__all(vmax - mrun[mi] <= 11.5f)) {  // defer-max (exp2 domain)
            const float mnew = fmaxf(mrun[mi], vmax);
            const float fs = fexp2(mrun[mi] - mnew);
            mrun[mi] = mnew;
            srun[mi] *= fs;
#pragma unroll
            for (int nd = 0; nd < 8; nd++)
#pragma unroll
              for (int r = 0; r < 4; r++) oacc[mi][nd][r] *= fs;
          }
          const float m = mrun[mi];
          float psum = 0.f;
#pragma unroll
          for (int ni = 0; ni < 4; ni++) {
            float p0 = fexp2(sa[mi][ni][0] - m);
            float p1 = fexp2(sa[mi][ni][1] - m);
            float p2 = fexp2(sa[mi][ni][2] - m);
            float p3 = fexp2(sa[mi][ni][3] - m);
            psum += (p0 + p1) + (p2 + p3);
            const int byteW =
                (((mi * 16 + ln) * 64 + ni * 16 + g * 4) * 2) ^ ((ln & 7) << 4);
            *(uint2*)((char*)(&Ps[w][0]) + byteW) =
                make_uint2(cvt_pk_bf16(p0, p1), cvt_pk_bf16(p2, p3));
          }
          psum += __shfl_xor(psum, 16);
          psum += __shfl_xor(psum, 32);
          srun[mi] += psum;
        }
        asm volatile("s_waitcnt lgkmcnt(0)" ::: "memory");
        __builtin_amdgcn_sched_barrier(0);
        __builtin_amdgcn_s_setprio(1);
#pragma unroll
        for (int ks = 0; ks < 2; ks++) {
          bf16x8 pf[2];
#pragma unroll
          for (int mi = 0; mi < 2; mi++) {
            const int byteR =
                (((mi * 16 + ln) * 64 + ks * 32 + g * 8) * 2) ^ ((ln & 7) << 4);
            pf[mi] = *(const bf16x8*)((const char*)(&Ps[w][0]) + byteR);
          }
#pragma unroll
          for (int nd = 0; nd < 8; nd++) {
            const int row = nd * 16 + ln;
            const int sl = (ks * 4 + g) ^ (row & 7);
            const bf16x8 vf = *(const bf16x8*)(Vst + row * 64 + sl * 8);
#pragma unroll
            for (int mi = 0; mi < 2; mi++)
              oacc[mi][nd] =
                  __builtin_amdgcn_mfma_f32_16x16x32_bf16(vf, pf[mi], oacc[mi][nd], 0, 0, 0);
          }
        }
        __builtin_amdgcn_s_setprio(0);
      }
      __builtin_amdgcn_s_barrier();
    }

    // ---- epilogue
    {
      ushort_t* Ob = O + (size_t)(b * S_ + q0 + w * 32) * E_ + h * D_;
#pragma unroll
      for (int mi = 0; mi < 2; mi++) {
        const float inv = 1.0f / srun[mi];
#pragma unroll
        for (int nd = 0; nd < 8; nd++) {
          const uint_t lo = cvt_pk_bf16(oacc[mi][nd][0] * inv, oacc[mi][nd][1] * inv);
          const uint_t hi = cvt_pk_bf16(oacc[mi][nd][2] * inv, oacc[mi][nd][3] * inv);
          *(uint2*)(Ob + (size_t)(mi * 16 + ln) * E_ + nd * 16 + g * 4) = make_uint2(lo, hi);
        }
      }
    }
  }
#undef STAGE_KV
}

// ---------------------------------------------------------------- launch
extern "C" void kernel_launch(void* const* d_in, const int* in_sizes, int n_in,
                              void* d_out, int out_size, void* d_ws, size_t ws_size,
                              hipStream_t stream) {
  const float* x = (const float*)d_in[0];
  const float* Wq = (const float*)d_in[1];
  const float* bq = (const float*)d_in[2];
  const float* Wk = (const float*)d_in[3];
  const float* bk = (const float*)d_in[4];
  const float* Wv = (const float*)d_in[5];
  const float* bv = (const float*)d_in[6];
  const float* Wo = (const float*)d_in[7];
  const float* bo = (const float*)d_in[8];
  float* out = (float*)d_out;

  ushort_t* ws = (ushort_t*)d_ws;
  const size_t SZ = (size_t)M_ * E_;   // 16,777,216
  const size_t WSZ = (size_t)E_ * E_;  // 4,194,304
  ushort_t* xb = ws;             // x bf16; reused as attention output
  ushort_t* Qb = ws + SZ;
  ushort_t* Kb = ws + 2 * SZ;
  ushort_t* Vtb = ws + 4 * SZ;   // [B][H][D][S], written directly by V epilogue
  ushort_t* Wqb = ws + 5 * SZ;   // 4 weights contiguous (Wq, Wk, Wv, Wo)
  ushort_t* Wob = Wqb + 3 * WSZ;
  float2* tbl = (float2*)(ws + 6 * SZ);  // 1 MB, after weights
  ushort_t* Ob = xb;

  const float scale2 = 0.12751744528276693f;  // D^-0.5 * log2(e), baked into Q

  prep<<<4608, 256, 0, stream>>>(x, Wq, Wk, Wv, Wo, xb, Wqb, tbl);

  qkv3<<<768, 512, 0, stream>>>(xb, Wqb, bq, bk, bv, tbl, scale2, Qb, Kb, Vtb);

  attn_fwd<<<512, 256, 0, stream>>>(Qb, Kb, Vtb, Ob);

  gemm_out<<<256, 512, 0, stream>>>(Ob, Wob, bo, out);
}